// Round 3
// baseline (1814.468 us; speedup 1.0000x reference)
//
#include <hip/hip_runtime.h>
#include <hip/hip_bf16.h>

// Workspace layout (floats). Total 36,175,872 floats + 1 int flag = ~145 MB.
// S3T  (2,512,512,16) @ 0
// YHR  (2,32,512,512) @ 8388608   -- reused as R3T (2,512,512,32) after S3 built
// LB0/1/2 (2,32,128,128) @ 25165824 / 26214400 / 27262976
// YLR  @ 28311552
// QT/S1T/S2T (2,128,128,16) @ 29360128 / 29884416 / 30408704
// R1T/R2T (2,128,128,32) @ 30932992 / 31981568
// BT1/2/3 (2,128,128,32) @ 33030144 / 34078720 / 35127296
// IDXFLAG (int) @ 36175872

// ---------------- index-dtype probe ----------------
// int64 little-endian values < 2^31 have all odd int32 words == 0.
// int32 data: 256 consecutive odd words are random in [0,128) -> OR != 0.
__global__ void idx_detect_kernel(const int* __restrict__ px, int* __restrict__ flag) {
  __shared__ int s;
  if (threadIdx.x == 0) s = 0;
  __syncthreads();
  int v = px[2 * threadIdx.x + 1];
  if (v != 0) atomicOr(&s, 1);
  __syncthreads();
  if (threadIdx.x == 0) *flag = (s == 0) ? 1 : 0;  // 1 => int64, 0 => int32
}

// ---------------- tiled 3x3 conv (32->32, pad=1) ----------------
// MODE 0: out = lrelu(conv(x,w))               NCHW
// MODE 1: out = conv(x,w) + res                NCHW
// MODE 2: t = conv(x,w) + res; out = 1x1(t)    channel-last (b,N,N,16)
template <int N, int MODE>
__global__ __launch_bounds__(256) void conv3x3_kernel(
    const float* __restrict__ x, const float* __restrict__ w,
    const float* __restrict__ res,
    const float* __restrict__ w1, const float* __restrict__ b1,
    float* __restrict__ out)
{
  __shared__ float tile[32][18][18];
  const int bx = blockIdx.x * 16, by = blockIdx.y * 16, bb = blockIdx.z;
  const int tx = threadIdx.x, ty = threadIdx.y;
  const int tid = ty * 16 + tx;
  const float* xb = x + (size_t)bb * 32 * N * N;

  for (int i = tid; i < 32 * 324; i += 256) {
    int ci = i / 324, rem = i % 324, r = rem / 18, c = rem % 18;
    int gy = by + r - 1, gx = bx + c - 1;
    float v = 0.f;
    if (gy >= 0 && gy < N && gx >= 0 && gx < N)
      v = xb[ci * N * N + gy * N + gx];
    tile[ci][r][c] = v;
  }
  __syncthreads();

  float acc[32];
#pragma unroll
  for (int co = 0; co < 32; ++co) acc[co] = 0.f;

  for (int ci = 0; ci < 32; ++ci) {
    float v[9];
#pragma unroll
    for (int dy = 0; dy < 3; ++dy)
#pragma unroll
      for (int dx = 0; dx < 3; ++dx)
        v[dy * 3 + dx] = tile[ci][ty + dy][tx + dx];
    const float* wc = w + ci * 9;        // w[(co*32+ci)*9 + t], uniform -> s_load
#pragma unroll
    for (int co = 0; co < 32; ++co) {
      const float* wp = wc + co * 288;
      float a = acc[co];
#pragma unroll
      for (int t = 0; t < 9; ++t) a = fmaf(v[t], wp[t], a);
      acc[co] = a;
    }
  }

  const int gy = by + ty, gx = bx + tx;
  const size_t pix = (size_t)gy * N + gx;
  if (MODE == 0) {
#pragma unroll
    for (int co = 0; co < 32; ++co) {
      float a = acc[co];
      a = a > 0.f ? a : 0.1f * a;
      out[((size_t)bb * 32 + co) * N * N + pix] = a;
    }
  } else if (MODE == 1) {
#pragma unroll
    for (int co = 0; co < 32; ++co)
      out[((size_t)bb * 32 + co) * N * N + pix] =
          acc[co] + res[((size_t)bb * 32 + co) * N * N + pix];
  } else {
    float t32[32];
#pragma unroll
    for (int co = 0; co < 32; ++co)
      t32[co] = acc[co] + res[((size_t)bb * 32 + co) * N * N + pix];
    float o16[16];
#pragma unroll
    for (int ct = 0; ct < 16; ++ct) {
      float s = b1[ct];
#pragma unroll
      for (int c = 0; c < 32; ++c) s = fmaf(w1[ct * 32 + c], t32[c], s);
      o16[ct] = s;
    }
    float4* op = (float4*)(out + (((size_t)bb * N + gy) * N + gx) * 16);
#pragma unroll
    for (int q = 0; q < 4; ++q) op[q] = ((float4*)o16)[q];
  }
}

// ---------------- 1x1 conv 32->16, channel-last output ----------------
__global__ __launch_bounds__(256) void conv1x1_16_kernel(
    const float* __restrict__ x, const float* __restrict__ w,
    const float* __restrict__ bias, float* __restrict__ out, int NP)
{
  int p = blockIdx.x * 256 + threadIdx.x;  // [0, 2*NP)
  int bb = p / NP, pp = p % NP;
  const float* xb = x + ((size_t)bb * 32) * NP + pp;
  float in[32];
#pragma unroll
  for (int c = 0; c < 32; ++c) in[c] = xb[(size_t)c * NP];
  float o[16];
#pragma unroll
  for (int ct = 0; ct < 16; ++ct) {
    float s = bias[ct];
#pragma unroll
    for (int c = 0; c < 32; ++c) s = fmaf(w[ct * 32 + c], in[c], s);
    o[ct] = s;
  }
  float4* op = (float4*)(out + (size_t)p * 16);
#pragma unroll
  for (int q = 0; q < 4; ++q) op[q] = ((float4*)o)[q];
}

// ---------------- NCHW (b,32,N,N) -> channel-last (b,N,N,32) ----------------
__global__ __launch_bounds__(256) void transpose_cl_kernel(
    const float* __restrict__ x, float* __restrict__ out, int NP)
{
  int p = blockIdx.x * 256 + threadIdx.x;
  int bb = p / NP, pp = p % NP;
  const float* xb = x + ((size_t)bb * 32) * NP + pp;
  float o[32];
#pragma unroll
  for (int c = 0; c < 32; ++c) o[c] = xb[(size_t)c * NP];
  float4* op = (float4*)(out + (size_t)p * 32);
#pragma unroll
  for (int q = 0; q < 8; ++q) op[q] = ((float4*)o)[q];
}

// ---------------- fepam: one wave64 per query, lane = neighbor ----------------
__global__ __launch_bounds__(256) void fepam_kernel(
    const float* __restrict__ Qt, const float* __restrict__ St,
    const float* __restrict__ Rt, const int* __restrict__ px,
    const int* __restrict__ py, const int* __restrict__ idxflag,
    float* __restrict__ out, int Ws, int HWs)
{
  const int wid = (blockIdx.x * 256 + threadIdx.x) >> 6;  // query id [0,32768)
  const int lane = threadIdx.x & 63;
  const int bb = wid >> 14;                               // 16384 queries/batch
  const float* qp = Qt + (size_t)wid * 16;
  const int f = *idxflag;                                 // 0:int32  1:int64
  const int j = (wid * 64 + lane) << f;                   // low word of elem if int64
  const int sidx = px[j] * Ws + py[j];

  const float* kp = St + ((size_t)bb * HWs + sidx) * 16;
  float score = 0.f;
#pragma unroll
  for (int c4 = 0; c4 < 4; ++c4) {
    float4 qv = ((const float4*)qp)[c4];
    float4 kv = ((const float4*)kp)[c4];
    score += qv.x * kv.x + qv.y * kv.y + qv.z * kv.z + qv.w * kv.w;
  }
  float m = score;
#pragma unroll
  for (int off = 32; off; off >>= 1) m = fmaxf(m, __shfl_xor(m, off));
  float e = __expf(score - m);
  float s = e;
#pragma unroll
  for (int off = 32; off; off >>= 1) s += __shfl_xor(s, off);
  float a = e / s;

  const float* vp = Rt + ((size_t)bb * HWs + sidx) * 32;
  float p[32];
#pragma unroll
  for (int c4 = 0; c4 < 8; ++c4) {
    float4 vv = ((const float4*)vp)[c4];
    p[c4 * 4 + 0] = a * vv.x; p[c4 * 4 + 1] = a * vv.y;
    p[c4 * 4 + 2] = a * vv.z; p[c4 * 4 + 3] = a * vv.w;
  }
#pragma unroll
  for (int off = 32; off; off >>= 1) {
#pragma unroll
    for (int c = 0; c < 32; ++c) p[c] += __shfl_xor(p[c], off);
  }
  if (lane == 0) {
    float4* op = (float4*)(out + (size_t)wid * 32);
#pragma unroll
    for (int q = 0; q < 8; ++q) op[q] = ((float4*)p)[q];
  }
}

// ---------------- final 1x1 over concat(b1,b2,b3,lb0) -> f32 NCHW ----------------
__global__ __launch_bounds__(256) void final_conv_kernel(
    const float* __restrict__ bt1, const float* __restrict__ bt2,
    const float* __restrict__ bt3, const float* __restrict__ lb0,
    const float* __restrict__ wf, const float* __restrict__ bfb,
    float* __restrict__ out)
{
  int p = blockIdx.x * 256 + threadIdx.x;  // [0,32768)
  int bb = p >> 14, pp = p & 16383;
  float in[128];
#pragma unroll
  for (int q = 0; q < 8; ++q) ((float4*)in)[q]        = ((const float4*)(bt1 + (size_t)p * 32))[q];
#pragma unroll
  for (int q = 0; q < 8; ++q) ((float4*)(in + 32))[q] = ((const float4*)(bt2 + (size_t)p * 32))[q];
#pragma unroll
  for (int q = 0; q < 8; ++q) ((float4*)(in + 64))[q] = ((const float4*)(bt3 + (size_t)p * 32))[q];
  const float* lp = lb0 + ((size_t)bb * 32) * 16384 + pp;
#pragma unroll
  for (int c = 0; c < 32; ++c) in[96 + c] = lp[(size_t)c * 16384];
#pragma unroll 2
  for (int co = 0; co < 32; ++co) {
    float s = bfb[co];
#pragma unroll
    for (int c = 0; c < 128; ++c) s = fmaf(wf[co * 128 + c], in[c], s);
    out[((size_t)bb * 32 + co) * 16384 + pp] = s;
  }
}

extern "C" void kernel_launch(void* const* d_in, const int* in_sizes, int n_in,
                              void* d_out, int out_size, void* d_ws, size_t ws_size,
                              hipStream_t stream)
{
  const float* lr0 = (const float*)d_in[0];
  const float* lr1 = (const float*)d_in[1];
  const float* lr2 = (const float*)d_in[2];
  const float* hr  = (const float*)d_in[3];
  const float* wl1 = (const float*)d_in[4];
  const float* wl2 = (const float*)d_in[5];
  const float* wh1 = (const float*)d_in[6];
  const float* wh2 = (const float*)d_in[7];
  const float* wq  = (const float*)d_in[8];
  const float* bq  = (const float*)d_in[9];
  const float* wk  = (const float*)d_in[10];
  const float* bk  = (const float*)d_in[11];
  const float* whk = (const float*)d_in[12];
  const float* bhk = (const float*)d_in[13];
  const float* wf  = (const float*)d_in[14];
  const float* bf  = (const float*)d_in[15];
  const int* px0 = (const int*)d_in[16];
  const int* py0 = (const int*)d_in[17];
  const int* px1 = (const int*)d_in[18];
  const int* py1 = (const int*)d_in[19];
  const int* px2 = (const int*)d_in[20];
  const int* py2 = (const int*)d_in[21];
  float* out = (float*)d_out;
  float* ws = (float*)d_ws;

  float* S3T = ws;
  float* YHR = ws + 8388608;   // reused as R3T after S3T is built
  float* R3T = YHR;
  float* LB0 = ws + 25165824;
  float* LB1 = ws + 26214400;
  float* LB2 = ws + 27262976;
  float* YLR = ws + 28311552;
  float* QT  = ws + 29360128;
  float* S1T = ws + 29884416;
  float* S2T = ws + 30408704;
  float* R1T = ws + 30932992;
  float* R2T = ws + 31981568;
  float* BT1 = ws + 33030144;
  float* BT2 = ws + 34078720;
  float* BT3 = ws + 35127296;
  int* IDXFLAG = (int*)(ws + 36175872);

  dim3 blk(16, 16);

  // index dtype probe (must precede fepam)
  idx_detect_kernel<<<1, 256, 0, stream>>>(px0, IDXFLAG);

  // hr branch: yhr = lrelu(conv(hr,wh1)); S3 = 1x1(conv(yhr,wh2)+hr) [hb never materialized]
  conv3x3_kernel<512, 0><<<dim3(32, 32, 2), blk, 0, stream>>>(hr, wh1, nullptr, nullptr, nullptr, YHR);
  conv3x3_kernel<512, 2><<<dim3(32, 32, 2), blk, 0, stream>>>(YHR, wh2, hr, whk, bhk, S3T);
  transpose_cl_kernel<<<2048, 256, 0, stream>>>(hr, R3T, 262144);

  // lr branches
  conv3x3_kernel<128, 0><<<dim3(8, 8, 2), blk, 0, stream>>>(lr0, wl1, nullptr, nullptr, nullptr, YLR);
  conv3x3_kernel<128, 1><<<dim3(8, 8, 2), blk, 0, stream>>>(YLR, wl2, lr0, nullptr, nullptr, LB0);
  conv3x3_kernel<128, 0><<<dim3(8, 8, 2), blk, 0, stream>>>(lr1, wl1, nullptr, nullptr, nullptr, YLR);
  conv3x3_kernel<128, 1><<<dim3(8, 8, 2), blk, 0, stream>>>(YLR, wl2, lr1, nullptr, nullptr, LB1);
  conv3x3_kernel<128, 0><<<dim3(8, 8, 2), blk, 0, stream>>>(lr2, wl1, nullptr, nullptr, nullptr, YLR);
  conv3x3_kernel<128, 1><<<dim3(8, 8, 2), blk, 0, stream>>>(YLR, wl2, lr2, nullptr, nullptr, LB2);

  // projections (channel-last) + transposed value tensors
  conv1x1_16_kernel<<<128, 256, 0, stream>>>(LB0, wq, bq, QT, 16384);
  conv1x1_16_kernel<<<128, 256, 0, stream>>>(LB1, wk, bk, S1T, 16384);
  conv1x1_16_kernel<<<128, 256, 0, stream>>>(LB2, wk, bk, S2T, 16384);
  transpose_cl_kernel<<<128, 256, 0, stream>>>(lr1, R1T, 16384);
  transpose_cl_kernel<<<128, 256, 0, stream>>>(lr2, R2T, 16384);

  // gather attention
  fepam_kernel<<<8192, 256, 0, stream>>>(QT, S1T, R1T, px0, py0, IDXFLAG, BT1, 128, 16384);
  fepam_kernel<<<8192, 256, 0, stream>>>(QT, S2T, R2T, px1, py1, IDXFLAG, BT2, 128, 16384);
  fepam_kernel<<<8192, 256, 0, stream>>>(QT, S3T, R3T, px2, py2, IDXFLAG, BT3, 512, 262144);

  // final fuse
  final_conv_kernel<<<128, 256, 0, stream>>>(BT1, BT2, BT3, LB0, wf, bf, out);
}

// Round 4
// 1530.503 us; speedup vs baseline: 1.1855x; 1.1855x over previous
//
#include <hip/hip_runtime.h>
#include <hip/hip_bf16.h>

// Workspace layout (floats).
// S3T  (2,512,512,16) @ 0
// YHR  (2,32,512,512) @ 8388608   -- reused as R3T (2,512,512,32) after S3 built
// LB0/1/2 (2,32,128,128) @ 25165824 / 26214400 / 27262976
// YLR  @ 28311552
// QT/S1T/S2T (2,128,128,16) @ 29360128 / 29884416 / 30408704
// R1T/R2T (2,128,128,32) @ 30932992 / 31981568
// BT1/2/3 (2,128,128,32) @ 33030144 / 34078720 / 35127296
// WT (4 x 9216) @ 36175872   -- weights transposed to [ci][co][9]
// IDXFLAG (int) @ 36212736

// ---------------- index-dtype probe ----------------
__global__ void idx_detect_kernel(const int* __restrict__ px, int* __restrict__ flag) {
  __shared__ int s;
  if (threadIdx.x == 0) s = 0;
  __syncthreads();
  int v = px[2 * threadIdx.x + 1];
  if (v != 0) atomicOr(&s, 1);
  __syncthreads();
  if (threadIdx.x == 0) *flag = (s == 0) ? 1 : 0;  // 1 => int64, 0 => int32
}

// ---------------- weight transpose: [co][ci][3][3] -> [ci][co][9] ----------------
__global__ __launch_bounds__(256) void wtrans_kernel(
    const float* __restrict__ w0, const float* __restrict__ w1,
    const float* __restrict__ w2, const float* __restrict__ w3,
    float* __restrict__ o0, float* __restrict__ o1,
    float* __restrict__ o2, float* __restrict__ o3)
{
  const float* w = blockIdx.y == 0 ? w0 : blockIdx.y == 1 ? w1 : blockIdx.y == 2 ? w2 : w3;
  float* o       = blockIdx.y == 0 ? o0 : blockIdx.y == 1 ? o1 : blockIdx.y == 2 ? o2 : o3;
  int i = blockIdx.x * 256 + threadIdx.x;  // [0, 9216)
  if (i < 9216) {
    int ci = i / 288, rem = i % 288, co = rem / 9, t = rem % 9;
    o[i] = w[(co * 32 + ci) * 9 + t];
  }
}

// ---------------- tiled 3x3 conv (32->32, pad=1), ci split in 2 LDS passes ----
// MODE 0: out = lrelu(conv(x,w))               NCHW
// MODE 1: out = conv(x,w) + res                NCHW
// MODE 2: t = conv(x,w) + res; out = 1x1(t)    channel-last (b,N,N,16)
// wT is the [ci][co][9] transposed weight.
template <int N, int MODE>
__global__ __launch_bounds__(256, 6) void conv3x3_kernel(
    const float* __restrict__ x, const float* __restrict__ wT,
    const float* __restrict__ res,
    const float* __restrict__ w1, const float* __restrict__ b1,
    float* __restrict__ out)
{
  __shared__ float tile[16 * 324];  // 16 ci x 18 x 18 = 20736 B
  const int bx = blockIdx.x * 16, by = blockIdx.y * 16, bb = blockIdx.z;
  const int tx = threadIdx.x, ty = threadIdx.y;
  const int tid = ty * 16 + tx;
  const float* xb = x + (size_t)bb * 32 * N * N;

  // staging slots: thread owns slot tid (and tid+256 if < 324); div/mod ONCE.
  const int r1 = tid / 18, c1 = tid % 18;
  const int gy1 = by + r1 - 1, gx1 = bx + c1 - 1;
  const int off1 = (gy1 >= 0 && gy1 < N && gx1 >= 0 && gx1 < N) ? gy1 * N + gx1 : -1;
  const int slot2 = tid + 256;
  const int r2 = slot2 / 18, c2 = slot2 % 18;
  const int gy2 = by + r2 - 1, gx2 = bx + c2 - 1;
  const int off2 = (slot2 < 324 && gy2 >= 0 && gy2 < N && gx2 >= 0 && gx2 < N) ? gy2 * N + gx2 : -1;
  const bool has2 = slot2 < 324;

  float acc[32];
#pragma unroll
  for (int co = 0; co < 32; ++co) acc[co] = 0.f;

  for (int half = 0; half < 2; ++half) {
    if (half) __syncthreads();
    const int cb = half * 16;
#pragma unroll 4
    for (int ci = 0; ci < 16; ++ci) {
      float v1 = off1 >= 0 ? xb[(size_t)(cb + ci) * N * N + off1] : 0.f;
      tile[ci * 324 + tid] = v1;
      if (has2) {
        float v2 = off2 >= 0 ? xb[(size_t)(cb + ci) * N * N + off2] : 0.f;
        tile[ci * 324 + slot2] = v2;
      }
    }
    __syncthreads();

    for (int ci = 0; ci < 16; ++ci) {
      float v[9];
#pragma unroll
      for (int dy = 0; dy < 3; ++dy)
#pragma unroll
        for (int dx = 0; dx < 3; ++dx)
          v[dy * 3 + dx] = tile[ci * 324 + (ty + dy) * 18 + (tx + dx)];
      const float* wp = wT + (size_t)(cb + ci) * 288;  // 288 contiguous, uniform
#pragma unroll
      for (int co = 0; co < 32; ++co) {
        float a = acc[co];
#pragma unroll
        for (int t = 0; t < 9; ++t) a = fmaf(v[t], wp[co * 9 + t], a);
        acc[co] = a;
      }
    }
  }

  const int gy = by + ty, gx = bx + tx;
  const size_t pix = (size_t)gy * N + gx;
  if (MODE == 0) {
#pragma unroll
    for (int co = 0; co < 32; ++co) {
      float a = acc[co];
      a = a > 0.f ? a : 0.1f * a;
      out[((size_t)bb * 32 + co) * N * N + pix] = a;
    }
  } else if (MODE == 1) {
#pragma unroll
    for (int co = 0; co < 32; ++co)
      out[((size_t)bb * 32 + co) * N * N + pix] =
          acc[co] + res[((size_t)bb * 32 + co) * N * N + pix];
  } else {
    float t32[32];
#pragma unroll
    for (int co = 0; co < 32; ++co)
      t32[co] = acc[co] + res[((size_t)bb * 32 + co) * N * N + pix];
    float o16[16];
#pragma unroll
    for (int ct = 0; ct < 16; ++ct) {
      float s = b1[ct];
#pragma unroll
      for (int c = 0; c < 32; ++c) s = fmaf(w1[ct * 32 + c], t32[c], s);
      o16[ct] = s;
    }
    float4* op = (float4*)(out + (((size_t)bb * N + gy) * N + gx) * 16);
#pragma unroll
    for (int q = 0; q < 4; ++q) op[q] = ((float4*)o16)[q];
  }
}

// ---------------- 1x1 conv 32->16, channel-last output ----------------
__global__ __launch_bounds__(256) void conv1x1_16_kernel(
    const float* __restrict__ x, const float* __restrict__ w,
    const float* __restrict__ bias, float* __restrict__ out, int NP)
{
  int p = blockIdx.x * 256 + threadIdx.x;
  int bb = p / NP, pp = p % NP;
  const float* xb = x + ((size_t)bb * 32) * NP + pp;
  float in[32];
#pragma unroll
  for (int c = 0; c < 32; ++c) in[c] = xb[(size_t)c * NP];
  float o[16];
#pragma unroll
  for (int ct = 0; ct < 16; ++ct) {
    float s = bias[ct];
#pragma unroll
    for (int c = 0; c < 32; ++c) s = fmaf(w[ct * 32 + c], in[c], s);
    o[ct] = s;
  }
  float4* op = (float4*)(out + (size_t)p * 16);
#pragma unroll
  for (int q = 0; q < 4; ++q) op[q] = ((float4*)o)[q];
}

// ---------------- NCHW (b,32,N,N) -> channel-last (b,N,N,32) ----------------
__global__ __launch_bounds__(256) void transpose_cl_kernel(
    const float* __restrict__ x, float* __restrict__ out, int NP)
{
  int p = blockIdx.x * 256 + threadIdx.x;
  int bb = p / NP, pp = p % NP;
  const float* xb = x + ((size_t)bb * 32) * NP + pp;
  float o[32];
#pragma unroll
  for (int c = 0; c < 32; ++c) o[c] = xb[(size_t)c * NP];
  float4* op = (float4*)(out + (size_t)p * 32);
#pragma unroll
  for (int q = 0; q < 8; ++q) op[q] = ((float4*)o)[q];
}

// ---------------- fepam: one wave64 per query, lane = neighbor ----------------
__global__ __launch_bounds__(256) void fepam_kernel(
    const float* __restrict__ Qt, const float* __restrict__ St,
    const float* __restrict__ Rt, const int* __restrict__ px,
    const int* __restrict__ py, const int* __restrict__ idxflag,
    float* __restrict__ out, int Ws, int HWs)
{
  const int wid = (blockIdx.x * 256 + threadIdx.x) >> 6;
  const int lane = threadIdx.x & 63;
  const int bb = wid >> 14;
  const float* qp = Qt + (size_t)wid * 16;
  const int f = *idxflag;                                 // 0:int32  1:int64
  const int j = (wid * 64 + lane) << f;
  const int sidx = px[j] * Ws + py[j];

  const float* kp = St + ((size_t)bb * HWs + sidx) * 16;
  float score = 0.f;
#pragma unroll
  for (int c4 = 0; c4 < 4; ++c4) {
    float4 qv = ((const float4*)qp)[c4];
    float4 kv = ((const float4*)kp)[c4];
    score += qv.x * kv.x + qv.y * kv.y + qv.z * kv.z + qv.w * kv.w;
  }
  float m = score;
#pragma unroll
  for (int off = 32; off; off >>= 1) m = fmaxf(m, __shfl_xor(m, off));
  float e = __expf(score - m);
  float s = e;
#pragma unroll
  for (int off = 32; off; off >>= 1) s += __shfl_xor(s, off);
  float a = e / s;

  const float* vp = Rt + ((size_t)bb * HWs + sidx) * 32;
  float p[32];
#pragma unroll
  for (int c4 = 0; c4 < 8; ++c4) {
    float4 vv = ((const float4*)vp)[c4];
    p[c4 * 4 + 0] = a * vv.x; p[c4 * 4 + 1] = a * vv.y;
    p[c4 * 4 + 2] = a * vv.z; p[c4 * 4 + 3] = a * vv.w;
  }
#pragma unroll
  for (int off = 32; off; off >>= 1) {
#pragma unroll
    for (int c = 0; c < 32; ++c) p[c] += __shfl_xor(p[c], off);
  }
  if (lane == 0) {
    float4* op = (float4*)(out + (size_t)wid * 32);
#pragma unroll
    for (int q = 0; q < 8; ++q) op[q] = ((float4*)p)[q];
  }
}

// ---------------- final 1x1 over concat(b1,b2,b3,lb0) -> f32 NCHW ----------------
__global__ __launch_bounds__(256) void final_conv_kernel(
    const float* __restrict__ bt1, const float* __restrict__ bt2,
    const float* __restrict__ bt3, const float* __restrict__ lb0,
    const float* __restrict__ wf, const float* __restrict__ bfb,
    float* __restrict__ out)
{
  int p = blockIdx.x * 256 + threadIdx.x;
  int bb = p >> 14, pp = p & 16383;
  float in[128];
#pragma unroll
  for (int q = 0; q < 8; ++q) ((float4*)in)[q]        = ((const float4*)(bt1 + (size_t)p * 32))[q];
#pragma unroll
  for (int q = 0; q < 8; ++q) ((float4*)(in + 32))[q] = ((const float4*)(bt2 + (size_t)p * 32))[q];
#pragma unroll
  for (int q = 0; q < 8; ++q) ((float4*)(in + 64))[q] = ((const float4*)(bt3 + (size_t)p * 32))[q];
  const float* lp = lb0 + ((size_t)bb * 32) * 16384 + pp;
#pragma unroll
  for (int c = 0; c < 32; ++c) in[96 + c] = lp[(size_t)c * 16384];
#pragma unroll 2
  for (int co = 0; co < 32; ++co) {
    float s = bfb[co];
#pragma unroll
    for (int c = 0; c < 128; ++c) s = fmaf(wf[co * 128 + c], in[c], s);
    out[((size_t)bb * 32 + co) * 16384 + pp] = s;
  }
}

extern "C" void kernel_launch(void* const* d_in, const int* in_sizes, int n_in,
                              void* d_out, int out_size, void* d_ws, size_t ws_size,
                              hipStream_t stream)
{
  const float* lr0 = (const float*)d_in[0];
  const float* lr1 = (const float*)d_in[1];
  const float* lr2 = (const float*)d_in[2];
  const float* hr  = (const float*)d_in[3];
  const float* wl1 = (const float*)d_in[4];
  const float* wl2 = (const float*)d_in[5];
  const float* wh1 = (const float*)d_in[6];
  const float* wh2 = (const float*)d_in[7];
  const float* wq  = (const float*)d_in[8];
  const float* bq  = (const float*)d_in[9];
  const float* wk  = (const float*)d_in[10];
  const float* bk  = (const float*)d_in[11];
  const float* whk = (const float*)d_in[12];
  const float* bhk = (const float*)d_in[13];
  const float* wf  = (const float*)d_in[14];
  const float* bf  = (const float*)d_in[15];
  const int* px0 = (const int*)d_in[16];
  const int* py0 = (const int*)d_in[17];
  const int* px1 = (const int*)d_in[18];
  const int* py1 = (const int*)d_in[19];
  const int* px2 = (const int*)d_in[20];
  const int* py2 = (const int*)d_in[21];
  float* out = (float*)d_out;
  float* ws = (float*)d_ws;

  float* S3T = ws;
  float* YHR = ws + 8388608;   // reused as R3T after S3T is built
  float* R3T = YHR;
  float* LB0 = ws + 25165824;
  float* LB1 = ws + 26214400;
  float* LB2 = ws + 27262976;
  float* YLR = ws + 28311552;
  float* QT  = ws + 29360128;
  float* S1T = ws + 29884416;
  float* S2T = ws + 30408704;
  float* R1T = ws + 30932992;
  float* R2T = ws + 31981568;
  float* BT1 = ws + 33030144;
  float* BT2 = ws + 34078720;
  float* BT3 = ws + 35127296;
  float* WTL1 = ws + 36175872;
  float* WTL2 = WTL1 + 9216;
  float* WTH1 = WTL2 + 9216;
  float* WTH2 = WTH1 + 9216;
  int* IDXFLAG = (int*)(WTH2 + 9216);

  dim3 blk(16, 16);

  // prep: index dtype probe + weight transposes
  idx_detect_kernel<<<1, 256, 0, stream>>>(px0, IDXFLAG);
  wtrans_kernel<<<dim3(36, 4), 256, 0, stream>>>(wl1, wl2, wh1, wh2, WTL1, WTL2, WTH1, WTH2);

  // hr branch: yhr = lrelu(conv(hr,wh1)); S3 = 1x1(conv(yhr,wh2)+hr)
  conv3x3_kernel<512, 0><<<dim3(32, 32, 2), blk, 0, stream>>>(hr, WTH1, nullptr, nullptr, nullptr, YHR);
  conv3x3_kernel<512, 2><<<dim3(32, 32, 2), blk, 0, stream>>>(YHR, WTH2, hr, whk, bhk, S3T);
  transpose_cl_kernel<<<2048, 256, 0, stream>>>(hr, R3T, 262144);

  // lr branches
  conv3x3_kernel<128, 0><<<dim3(8, 8, 2), blk, 0, stream>>>(lr0, WTL1, nullptr, nullptr, nullptr, YLR);
  conv3x3_kernel<128, 1><<<dim3(8, 8, 2), blk, 0, stream>>>(YLR, WTL2, lr0, nullptr, nullptr, LB0);
  conv3x3_kernel<128, 0><<<dim3(8, 8, 2), blk, 0, stream>>>(lr1, WTL1, nullptr, nullptr, nullptr, YLR);
  conv3x3_kernel<128, 1><<<dim3(8, 8, 2), blk, 0, stream>>>(YLR, WTL2, lr1, nullptr, nullptr, LB1);
  conv3x3_kernel<128, 0><<<dim3(8, 8, 2), blk, 0, stream>>>(lr2, WTL1, nullptr, nullptr, nullptr, YLR);
  conv3x3_kernel<128, 1><<<dim3(8, 8, 2), blk, 0, stream>>>(YLR, WTL2, lr2, nullptr, nullptr, LB2);

  // projections (channel-last) + transposed value tensors
  conv1x1_16_kernel<<<128, 256, 0, stream>>>(LB0, wq, bq, QT, 16384);
  conv1x1_16_kernel<<<128, 256, 0, stream>>>(LB1, wk, bk, S1T, 16384);
  conv1x1_16_kernel<<<128, 256, 0, stream>>>(LB2, wk, bk, S2T, 16384);
  transpose_cl_kernel<<<128, 256, 0, stream>>>(lr1, R1T, 16384);
  transpose_cl_kernel<<<128, 256, 0, stream>>>(lr2, R2T, 16384);

  // gather attention
  fepam_kernel<<<8192, 256, 0, stream>>>(QT, S1T, R1T, px0, py0, IDXFLAG, BT1, 128, 16384);
  fepam_kernel<<<8192, 256, 0, stream>>>(QT, S2T, R2T, px1, py1, IDXFLAG, BT2, 128, 16384);
  fepam_kernel<<<8192, 256, 0, stream>>>(QT, S3T, R3T, px2, py2, IDXFLAG, BT3, 512, 262144);

  // final fuse
  final_conv_kernel<<<128, 256, 0, stream>>>(BT1, BT2, BT3, LB0, wf, bf, out);
}

// Round 5
// 1119.258 us; speedup vs baseline: 1.6211x; 1.3674x over previous
//
#include <hip/hip_runtime.h>
#include <hip/hip_bf16.h>

// Workspace layout (floats) — unchanged from round 4.
// S3T  (2,512,512,16) @ 0
// YHR  (2,32,512,512) @ 8388608   -- reused as R3T (2,512,512,32) after S3 built
// LB0/1/2 (2,32,128,128) @ 25165824 / 26214400 / 27262976
// YLR (unused now) @ 28311552
// QT/S1T/S2T (2,128,128,16) @ 29360128 / 29884416 / 30408704
// R1T/R2T (2,128,128,32) @ 30932992 / 31981568
// BT1/2/3 (2,128,128,32) @ 33030144 / 34078720 / 35127296  (also lr-conv scratch)
// WT (4 x 9216) @ 36175872   -- weights transposed to [ci][co][9]
// IDXFLAG (int) @ 36212736

struct In3  { const float* p[3]; };
struct Out3 { float* p[3]; };

// ---------------- index-dtype probe ----------------
__global__ void idx_detect_kernel(const int* __restrict__ px, int* __restrict__ flag) {
  __shared__ int s;
  if (threadIdx.x == 0) s = 0;
  __syncthreads();
  int v = px[2 * threadIdx.x + 1];
  if (v != 0) atomicOr(&s, 1);
  __syncthreads();
  if (threadIdx.x == 0) *flag = (s == 0) ? 1 : 0;  // 1 => int64, 0 => int32
}

// ---------------- weight transpose: [co][ci][3][3] -> [ci][co][9] ----------------
__global__ __launch_bounds__(256) void wtrans_kernel(
    const float* __restrict__ w0, const float* __restrict__ w1,
    const float* __restrict__ w2, const float* __restrict__ w3,
    float* __restrict__ o0, float* __restrict__ o1,
    float* __restrict__ o2, float* __restrict__ o3)
{
  const float* w = blockIdx.y == 0 ? w0 : blockIdx.y == 1 ? w1 : blockIdx.y == 2 ? w2 : w3;
  float* o       = blockIdx.y == 0 ? o0 : blockIdx.y == 1 ? o1 : blockIdx.y == 2 ? o2 : o3;
  int i = blockIdx.x * 256 + threadIdx.x;  // [0, 9216)
  if (i < 9216) {
    int ci = i / 288, rem = i % 288, co = rem / 9, t = rem % 9;
    o[i] = w[(co * 32 + ci) * 9 + t];
  }
}

// ---------------- tiled 3x3 conv (32->32, pad=1), 2 px/thread ----------------
// Tile: 16 wide x 32 tall. Thread (tx,ty) owns px (2ty, tx) and (2ty+1, tx).
// ci staged in 4 passes of 8 channels; LDS [8][34][19] (pitch-19 padding).
// MODE 0: out = lrelu(conv)        MODE 1: out = conv + res
// MODE 2: t = conv + res; out = 1x1_16(t) channel-last
// Batched over tensors: blockIdx.z = tensor*2 + batch.
template <int N, int MODE>
__global__ __launch_bounds__(256, 4) void conv3x3_kernel(
    In3 xs, const float* __restrict__ wT, In3 rs,
    const float* __restrict__ w1, const float* __restrict__ b1, Out3 os)
{
  __shared__ float tile[8 * 646];  // 8 ci x 34 rows x pitch 19 = 20672 B
  const int bx = blockIdx.x * 16, by = blockIdx.y * 32;
  const int tn = blockIdx.z >> 1, bb = blockIdx.z & 1;
  const int tx = threadIdx.x, ty = threadIdx.y;
  const int tid = ty * 16 + tx;
  const float* xb = xs.p[tn] + (size_t)bb * 32 * N * N;

  // staging slots (34x18 logical = 612): tid, tid+256, tid+512(<612)
  const int r1 = tid / 18, c1 = tid % 18;
  const int gy1 = by + r1 - 1, gx1 = bx + c1 - 1;
  const int off1 = (gy1 >= 0 && gy1 < N && gx1 >= 0 && gx1 < N) ? gy1 * N + gx1 : -1;
  const int l1 = r1 * 19 + c1;
  const int s2 = tid + 256;
  const int r2 = s2 / 18, c2 = s2 % 18;
  const int gy2 = by + r2 - 1, gx2 = bx + c2 - 1;
  const int off2 = (gy2 >= 0 && gy2 < N && gx2 >= 0 && gx2 < N) ? gy2 * N + gx2 : -1;
  const int l2 = r2 * 19 + c2;
  const int s3 = tid + 512;
  const bool has3 = s3 < 612;
  const int r3 = s3 / 18, c3 = s3 % 18;
  const int gy3 = by + r3 - 1, gx3 = bx + c3 - 1;
  const int off3 = (has3 && gy3 >= 0 && gy3 < N && gx3 >= 0 && gx3 < N) ? gy3 * N + gx3 : -1;
  const int l3 = r3 * 19 + c3;

  float acc0[32], acc1[32];
#pragma unroll
  for (int co = 0; co < 32; ++co) { acc0[co] = 0.f; acc1[co] = 0.f; }

  for (int pass = 0; pass < 4; ++pass) {
    if (pass) __syncthreads();
    const int cb = pass * 8;
#pragma unroll
    for (int ci = 0; ci < 8; ++ci) {
      const float* xc = xb + (size_t)(cb + ci) * N * N;
      tile[ci * 646 + l1] = off1 >= 0 ? xc[off1] : 0.f;
      tile[ci * 646 + l2] = off2 >= 0 ? xc[off2] : 0.f;
      if (has3) tile[ci * 646 + l3] = off3 >= 0 ? xc[off3] : 0.f;
    }
    __syncthreads();

    for (int ci = 0; ci < 8; ++ci) {
      float v[4][3];
#pragma unroll
      for (int dy = 0; dy < 4; ++dy)
#pragma unroll
        for (int dx = 0; dx < 3; ++dx)
          v[dy][dx] = tile[ci * 646 + (2 * ty + dy) * 19 + (tx + dx)];
      const float* wp = wT + (size_t)(cb + ci) * 288;  // uniform -> s_load
#pragma unroll
      for (int co = 0; co < 32; ++co) {
        float a0 = acc0[co], a1 = acc1[co];
#pragma unroll
        for (int dy = 0; dy < 3; ++dy)
#pragma unroll
          for (int dx = 0; dx < 3; ++dx) {
            const float wv = wp[co * 9 + dy * 3 + dx];
            a0 = fmaf(v[dy][dx], wv, a0);
            a1 = fmaf(v[dy + 1][dx], wv, a1);
          }
        acc0[co] = a0; acc1[co] = a1;
      }
    }
  }

  const int gx = bx + tx, gy0 = by + 2 * ty, gy1o = gy0 + 1;
  float* ob = os.p[tn];
  const size_t pix0 = (size_t)gy0 * N + gx, pix1 = (size_t)gy1o * N + gx;
  if (MODE == 0) {
#pragma unroll
    for (int co = 0; co < 32; ++co) {
      float a = acc0[co], c = acc1[co];
      a = a > 0.f ? a : 0.1f * a;
      c = c > 0.f ? c : 0.1f * c;
      ob[((size_t)bb * 32 + co) * N * N + pix0] = a;
      ob[((size_t)bb * 32 + co) * N * N + pix1] = c;
    }
  } else if (MODE == 1) {
    const float* rb = rs.p[tn] + (size_t)bb * 32 * N * N;
#pragma unroll
    for (int co = 0; co < 32; ++co) {
      ob[((size_t)bb * 32 + co) * N * N + pix0] = acc0[co] + rb[(size_t)co * N * N + pix0];
      ob[((size_t)bb * 32 + co) * N * N + pix1] = acc1[co] + rb[(size_t)co * N * N + pix1];
    }
  } else {
    const float* rb = rs.p[tn] + (size_t)bb * 32 * N * N;
#pragma unroll
    for (int co = 0; co < 32; ++co) {
      acc0[co] += rb[(size_t)co * N * N + pix0];
      acc1[co] += rb[(size_t)co * N * N + pix1];
    }
    float o16[16];
#pragma unroll
    for (int ct = 0; ct < 16; ++ct) {
      float s = b1[ct];
#pragma unroll
      for (int c = 0; c < 32; ++c) s = fmaf(w1[ct * 32 + c], acc0[c], s);
      o16[ct] = s;
    }
    float4* op0 = (float4*)(ob + (((size_t)bb * N + gy0) * N + gx) * 16);
#pragma unroll
    for (int q = 0; q < 4; ++q) op0[q] = ((float4*)o16)[q];
#pragma unroll
    for (int ct = 0; ct < 16; ++ct) {
      float s = b1[ct];
#pragma unroll
      for (int c = 0; c < 32; ++c) s = fmaf(w1[ct * 32 + c], acc1[c], s);
      o16[ct] = s;
    }
    float4* op1 = (float4*)(ob + (((size_t)bb * N + gy1o) * N + gx) * 16);
#pragma unroll
    for (int q = 0; q < 4; ++q) op1[q] = ((float4*)o16)[q];
  }
}

// ---------------- 1x1 conv 32->16, channel-last output ----------------
__global__ __launch_bounds__(256) void conv1x1_16_kernel(
    const float* __restrict__ x, const float* __restrict__ w,
    const float* __restrict__ bias, float* __restrict__ out, int NP)
{
  int p = blockIdx.x * 256 + threadIdx.x;
  int bb = p / NP, pp = p % NP;
  const float* xb = x + ((size_t)bb * 32) * NP + pp;
  float in[32];
#pragma unroll
  for (int c = 0; c < 32; ++c) in[c] = xb[(size_t)c * NP];
  float o[16];
#pragma unroll
  for (int ct = 0; ct < 16; ++ct) {
    float s = bias[ct];
#pragma unroll
    for (int c = 0; c < 32; ++c) s = fmaf(w[ct * 32 + c], in[c], s);
    o[ct] = s;
  }
  float4* op = (float4*)(out + (size_t)p * 16);
#pragma unroll
  for (int q = 0; q < 4; ++q) op[q] = ((float4*)o)[q];
}

// ---------------- NCHW (b,32,N,N) -> channel-last (b,N,N,32) ----------------
__global__ __launch_bounds__(256) void transpose_cl_kernel(
    const float* __restrict__ x, float* __restrict__ out, int NP)
{
  int p = blockIdx.x * 256 + threadIdx.x;
  int bb = p / NP, pp = p % NP;
  const float* xb = x + ((size_t)bb * 32) * NP + pp;
  float o[32];
#pragma unroll
  for (int c = 0; c < 32; ++c) o[c] = xb[(size_t)c * NP];
  float4* op = (float4*)(out + (size_t)p * 32);
#pragma unroll
  for (int q = 0; q < 8; ++q) op[q] = ((float4*)o)[q];
}

// ---------------- fepam: one wave64 per query, lane = neighbor ----------------
__global__ __launch_bounds__(256) void fepam_kernel(
    const float* __restrict__ Qt, const float* __restrict__ St,
    const float* __restrict__ Rt, const int* __restrict__ px,
    const int* __restrict__ py, const int* __restrict__ idxflag,
    float* __restrict__ out, int Ws, int HWs)
{
  const int wid = (blockIdx.x * 256 + threadIdx.x) >> 6;
  const int lane = threadIdx.x & 63;
  const int bb = wid >> 14;
  const float* qp = Qt + (size_t)wid * 16;
  const int f = *idxflag;                                 // 0:int32  1:int64
  const int j = (wid * 64 + lane) << f;
  const int sidx = px[j] * Ws + py[j];

  const float* kp = St + ((size_t)bb * HWs + sidx) * 16;
  float score = 0.f;
#pragma unroll
  for (int c4 = 0; c4 < 4; ++c4) {
    float4 qv = ((const float4*)qp)[c4];
    float4 kv = ((const float4*)kp)[c4];
    score += qv.x * kv.x + qv.y * kv.y + qv.z * kv.z + qv.w * kv.w;
  }
  float m = score;
#pragma unroll
  for (int off = 32; off; off >>= 1) m = fmaxf(m, __shfl_xor(m, off));
  float e = __expf(score - m);
  float s = e;
#pragma unroll
  for (int off = 32; off; off >>= 1) s += __shfl_xor(s, off);
  float a = e / s;

  const float* vp = Rt + ((size_t)bb * HWs + sidx) * 32;
  float p[32];
#pragma unroll
  for (int c4 = 0; c4 < 8; ++c4) {
    float4 vv = ((const float4*)vp)[c4];
    p[c4 * 4 + 0] = a * vv.x; p[c4 * 4 + 1] = a * vv.y;
    p[c4 * 4 + 2] = a * vv.z; p[c4 * 4 + 3] = a * vv.w;
  }
#pragma unroll
  for (int off = 32; off; off >>= 1) {
#pragma unroll
    for (int c = 0; c < 32; ++c) p[c] += __shfl_xor(p[c], off);
  }
  if (lane == 0) {
    float4* op = (float4*)(out + (size_t)wid * 32);
#pragma unroll
    for (int q = 0; q < 8; ++q) op[q] = ((float4*)p)[q];
  }
}

// ---------------- final 1x1 over concat(b1,b2,b3,lb0) -> f32 NCHW ----------------
__global__ __launch_bounds__(256) void final_conv_kernel(
    const float* __restrict__ bt1, const float* __restrict__ bt2,
    const float* __restrict__ bt3, const float* __restrict__ lb0,
    const float* __restrict__ wf, const float* __restrict__ bfb,
    float* __restrict__ out)
{
  int p = blockIdx.x * 256 + threadIdx.x;
  int bb = p >> 14, pp = p & 16383;
  float in[128];
#pragma unroll
  for (int q = 0; q < 8; ++q) ((float4*)in)[q]        = ((const float4*)(bt1 + (size_t)p * 32))[q];
#pragma unroll
  for (int q = 0; q < 8; ++q) ((float4*)(in + 32))[q] = ((const float4*)(bt2 + (size_t)p * 32))[q];
#pragma unroll
  for (int q = 0; q < 8; ++q) ((float4*)(in + 64))[q] = ((const float4*)(bt3 + (size_t)p * 32))[q];
  const float* lp = lb0 + ((size_t)bb * 32) * 16384 + pp;
#pragma unroll
  for (int c = 0; c < 32; ++c) in[96 + c] = lp[(size_t)c * 16384];
#pragma unroll 2
  for (int co = 0; co < 32; ++co) {
    float s = bfb[co];
#pragma unroll
    for (int c = 0; c < 128; ++c) s = fmaf(wf[co * 128 + c], in[c], s);
    out[((size_t)bb * 32 + co) * 16384 + pp] = s;
  }
}

extern "C" void kernel_launch(void* const* d_in, const int* in_sizes, int n_in,
                              void* d_out, int out_size, void* d_ws, size_t ws_size,
                              hipStream_t stream)
{
  const float* lr0 = (const float*)d_in[0];
  const float* lr1 = (const float*)d_in[1];
  const float* lr2 = (const float*)d_in[2];
  const float* hr  = (const float*)d_in[3];
  const float* wl1 = (const float*)d_in[4];
  const float* wl2 = (const float*)d_in[5];
  const float* wh1 = (const float*)d_in[6];
  const float* wh2 = (const float*)d_in[7];
  const float* wq  = (const float*)d_in[8];
  const float* bq  = (const float*)d_in[9];
  const float* wk  = (const float*)d_in[10];
  const float* bk  = (const float*)d_in[11];
  const float* whk = (const float*)d_in[12];
  const float* bhk = (const float*)d_in[13];
  const float* wf  = (const float*)d_in[14];
  const float* bf  = (const float*)d_in[15];
  const int* px0 = (const int*)d_in[16];
  const int* py0 = (const int*)d_in[17];
  const int* px1 = (const int*)d_in[18];
  const int* py1 = (const int*)d_in[19];
  const int* px2 = (const int*)d_in[20];
  const int* py2 = (const int*)d_in[21];
  float* out = (float*)d_out;
  float* ws = (float*)d_ws;

  float* S3T = ws;
  float* YHR = ws + 8388608;   // reused as R3T after S3T is built
  float* R3T = YHR;
  float* LB0 = ws + 25165824;
  float* LB1 = ws + 26214400;
  float* LB2 = ws + 27262976;
  float* QT  = ws + 29360128;
  float* S1T = ws + 29884416;
  float* S2T = ws + 30408704;
  float* R1T = ws + 30932992;
  float* R2T = ws + 31981568;
  float* BT1 = ws + 33030144;  // also lr-conv1 scratch (before fepam)
  float* BT2 = ws + 34078720;
  float* BT3 = ws + 35127296;
  float* WTL1 = ws + 36175872;
  float* WTL2 = WTL1 + 9216;
  float* WTH1 = WTL2 + 9216;
  float* WTH2 = WTH1 + 9216;
  int* IDXFLAG = (int*)(WTH2 + 9216);

  dim3 blk(16, 16);

  // prep: index dtype probe + weight transposes
  idx_detect_kernel<<<1, 256, 0, stream>>>(px0, IDXFLAG);
  wtrans_kernel<<<dim3(36, 4), 256, 0, stream>>>(wl1, wl2, wh1, wh2, WTL1, WTL2, WTH1, WTH2);

  In3 none{};
  // hr branch: yhr = lrelu(conv(hr,wh1)); S3 = 1x1(conv(yhr,wh2)+hr)
  conv3x3_kernel<512, 0><<<dim3(32, 16, 2), blk, 0, stream>>>(
      In3{{hr}}, WTH1, none, nullptr, nullptr, Out3{{YHR}});
  conv3x3_kernel<512, 2><<<dim3(32, 16, 2), blk, 0, stream>>>(
      In3{{YHR}}, WTH2, In3{{hr}}, whk, bhk, Out3{{S3T}});
  transpose_cl_kernel<<<2048, 256, 0, stream>>>(hr, R3T, 262144);

  // lr branches, batched over the 3 tensors (shared weights)
  conv3x3_kernel<128, 0><<<dim3(8, 4, 6), blk, 0, stream>>>(
      In3{{lr0, lr1, lr2}}, WTL1, none, nullptr, nullptr, Out3{{BT1, BT2, BT3}});
  conv3x3_kernel<128, 1><<<dim3(8, 4, 6), blk, 0, stream>>>(
      In3{{BT1, BT2, BT3}}, WTL2, In3{{lr0, lr1, lr2}}, nullptr, nullptr,
      Out3{{LB0, LB1, LB2}});

  // projections (channel-last) + transposed value tensors
  conv1x1_16_kernel<<<128, 256, 0, stream>>>(LB0, wq, bq, QT, 16384);
  conv1x1_16_kernel<<<128, 256, 0, stream>>>(LB1, wk, bk, S1T, 16384);
  conv1x1_16_kernel<<<128, 256, 0, stream>>>(LB2, wk, bk, S2T, 16384);
  transpose_cl_kernel<<<128, 256, 0, stream>>>(lr1, R1T, 16384);
  transpose_cl_kernel<<<128, 256, 0, stream>>>(lr2, R2T, 16384);

  // gather attention
  fepam_kernel<<<8192, 256, 0, stream>>>(QT, S1T, R1T, px0, py0, IDXFLAG, BT1, 128, 16384);
  fepam_kernel<<<8192, 256, 0, stream>>>(QT, S2T, R2T, px1, py1, IDXFLAG, BT2, 128, 16384);
  fepam_kernel<<<8192, 256, 0, stream>>>(QT, S3T, R3T, px2, py2, IDXFLAG, BT3, 512, 262144);

  // final fuse
  final_conv_kernel<<<128, 256, 0, stream>>>(BT1, BT2, BT3, LB0, wf, bf, out);
}

// Round 6
// 736.696 us; speedup vs baseline: 2.4630x; 1.5193x over previous
//
#include <hip/hip_runtime.h>
#include <hip/hip_bf16.h>

typedef short bfv8 __attribute__((ext_vector_type(8)));
typedef float f4v __attribute__((ext_vector_type(4)));

static __device__ __forceinline__ unsigned short f2bf(float f) {
  unsigned u = __float_as_uint(f);
  unsigned r = (u + 0x7FFFu + ((u >> 16) & 1u)) >> 16;
  return (unsigned short)r;
}

// Workspace (floats):
// S3T (2,512,512,16) @0..8388608
// R3T (2,512,512,32) @8388608..25165824   [HRC bf16 aliased @16777216..25165824, dead before R3T written]
// YC bf16 @25165824..33554432             [dead before LB*/QT/S*/R*/BT1 written]
// LB0/1/2 @25165824/26214400/27262976 ; QT/S1T/S2T @29360128/29884416/30408704
// R1T/R2T @30932992/31981568 ; BT1/2/3 @33030144/34078720/35127296
// WTL1/WTL2 f32 @36175872/36185088 ; WB1/WB2 bf16 @36194304/36198912 ; WHKB @36203520 ; IDXFLAG @36203776

struct In3  { const float* p[3]; };
struct Out3 { float* p[3]; };

// ---------------- index-dtype probe ----------------
__global__ void idx_detect_kernel(const int* __restrict__ px, int* __restrict__ flag) {
  __shared__ int s;
  if (threadIdx.x == 0) s = 0;
  __syncthreads();
  int v = px[2 * threadIdx.x + 1];
  if (v != 0) atomicOr(&s, 1);
  __syncthreads();
  if (threadIdx.x == 0) *flag = (s == 0) ? 1 : 0;  // 1 => int64, 0 => int32
}

// ---------------- f32 weight transpose (lr convs): [co][ci][3][3] -> [ci][co][9] ----
__global__ __launch_bounds__(256) void wtrans_kernel(
    const float* __restrict__ w0, const float* __restrict__ w1,
    float* __restrict__ o0, float* __restrict__ o1)
{
  const float* w = blockIdx.y ? w1 : w0;
  float* o       = blockIdx.y ? o1 : o0;
  int i = blockIdx.x * 256 + threadIdx.x;
  if (i < 9216) {
    int ci = i / 288, rem = i % 288, co = rem / 9, t = rem % 9;
    o[i] = w[(co * 32 + ci) * 9 + t];
  }
}

// ---------------- bf16 weight prep (hr convs): -> [tap][co][ci] ----------------
__global__ __launch_bounds__(256) void wconv_bf16_kernel(
    const float* __restrict__ wh1, const float* __restrict__ wh2,
    const float* __restrict__ whk,
    unsigned short* __restrict__ o1, unsigned short* __restrict__ o2,
    unsigned short* __restrict__ ok)
{
  int i = blockIdx.x * 256 + threadIdx.x;
  if (blockIdx.y < 2) {
    const float* w = blockIdx.y ? wh2 : wh1;
    unsigned short* o = blockIdx.y ? o2 : o1;
    if (i < 9216) {
      int t = i / 1024, rem = i % 1024, co = rem >> 5, ci = rem & 31;
      o[i] = f2bf(w[(co * 32 + ci) * 9 + t]);
    }
  } else if (i < 512) {
    ok[i] = f2bf(whk[i]);
  }
}

// ---------------- hr NCHW f32 -> channel-last bf16 ----------------
__global__ __launch_bounds__(256) void hrc_kernel(
    const float* __restrict__ x, unsigned short* __restrict__ o)
{
  int p = blockIdx.x * 256 + threadIdx.x;  // [0, 524288)
  int bb = p >> 18, pp = p & 262143;
  const float* xb = x + ((size_t)bb * 32) * 262144 + pp;
  unsigned short v[32];
#pragma unroll
  for (int c = 0; c < 32; ++c) v[c] = f2bf(xb[(size_t)c * 262144]);
  uint4* op = (uint4*)(o + (size_t)p * 32);
#pragma unroll
  for (int q = 0; q < 4; ++q) op[q] = ((uint4*)v)[q];
}

// ---------------- MFMA 3x3 conv, N=512, bf16 channel-last ----------------
// Block: 8 rows x 64 cols of output, 4 waves; wave w: rows 2w..2w+1 (128 px x 32 co).
// A = weights [tap][32co][32ci] (register-resident), B = pixels from swizzled LDS tile.
// MODE 0: YC = lrelu(conv)  (bf16 CL)
// MODE 2: hb = conv + hr(f32 NCHW); S3T = whk*hb + bhk (f32 CL 16ch); hb discarded.
#define CTILE 42240  // 10 rows x 66 px x 64B
template <int MODE>
__global__ __launch_bounds__(256, 2) void conv_mfma_kernel(
    const unsigned short* __restrict__ X, const unsigned short* __restrict__ WB,
    const float* __restrict__ hr, const unsigned short* __restrict__ WHKB,
    const float* __restrict__ bhk, void* __restrict__ outp)
{
  __shared__ uint4 smem_[3856];  // 61696 B: tile 42240 | conv W 18432 | whk 1024
  unsigned char* smem = (unsigned char*)smem_;
  const int bx0 = blockIdx.x * 64, by0 = blockIdx.y * 8, bb = blockIdx.z;
  const int tid = threadIdx.x;
  const int w = tid >> 6, lane = tid & 63;
  const int l15 = lane & 15, ch = lane >> 4;

  // stage input tile (rows by0-1..by0+8, px bx0-1..bx0+64, 32ch bf16), XOR-swizzled
  const unsigned short* Xb = X + (size_t)bb * 512 * 512 * 32;
  for (int g = tid; g < 2640; g += 256) {
    int row = g / 264, rem = g - row * 264;
    int px = rem >> 2, c4 = rem & 3;
    int gy = by0 + row - 1, gx = bx0 + px - 1;
    uint4 v = {0u, 0u, 0u, 0u};
    if (gy >= 0 && gy < 512 && gx >= 0 && gx < 512)
      v = *(const uint4*)(Xb + (size_t)(gy * 512 + gx) * 32 + c4 * 8);
    int byt = (row * 4224 + px * 64 + c4 * 16) ^ ((px & 7) << 4);
    *(uint4*)(smem + byt) = v;
  }
  for (int g = tid; g < 1152; g += 256)
    *(uint4*)(smem + CTILE + g * 16) = *(const uint4*)(WB + g * 8);
  if (MODE == 2) {
    if (tid < 64)
      *(uint4*)(smem + CTILE + 18432 + tid * 16) = *(const uint4*)(WHKB + tid * 8);
  }
  __syncthreads();

  // weight A-fragments -> registers (row = co, k = ci)
  bfv8 wa[9][2];
#pragma unroll
  for (int t = 0; t < 9; ++t)
#pragma unroll
    for (int j = 0; j < 2; ++j)
      wa[t][j] = *(bfv8*)(smem + CTILE + t * 2048 + (16 * j + l15) * 64 + ch * 16);

  f4v acc[2][8];
#pragma unroll
  for (int j = 0; j < 2; ++j)
#pragma unroll
    for (int f = 0; f < 8; ++f) acc[j][f] = (f4v){0.f, 0.f, 0.f, 0.f};

#pragma unroll
  for (int dy = 0; dy < 3; ++dy)
#pragma unroll
    for (int dx = 0; dx < 3; ++dx)
#pragma unroll
      for (int f = 0; f < 8; ++f) {
        const int hrow = 2 * w + (f >> 2) + dy;
        const int xh = 16 * (f & 3) + l15 + dx;
        const int byt = (hrow * 4224 + xh * 64 + ch * 16) ^ ((xh & 7) << 4);
        bfv8 b = *(bfv8*)(smem + byt);
        acc[0][f] = __builtin_amdgcn_mfma_f32_16x16x32_bf16(wa[dy * 3 + dx][0], b, acc[0][f], 0, 0, 0);
        acc[1][f] = __builtin_amdgcn_mfma_f32_16x16x32_bf16(wa[dy * 3 + dx][1], b, acc[1][f], 0, 0, 0);
      }

  // D layout: row (=co within frag) = ch*4+i, col (=px within frag) = l15
  if (MODE == 0) {
    unsigned short* YC = (unsigned short*)outp;
#pragma unroll
    for (int j = 0; j < 2; ++j)
#pragma unroll
      for (int f = 0; f < 8; ++f) {
        const int gy = by0 + 2 * w + (f >> 2);
        const int gx = bx0 + 16 * (f & 3) + l15;
        const int co0 = 16 * j + ch * 4;
        unsigned short o[4];
#pragma unroll
        for (int i = 0; i < 4; ++i) {
          float a = acc[j][f][i];
          a = a > 0.f ? a : 0.1f * a;
          o[i] = f2bf(a);
        }
        *(uint2*)(YC + (size_t)bb * 8388608 + (size_t)(gy * 512 + gx) * 32 + co0) = *(uint2*)o;
      }
  } else {
    // residual add (hr is f32 NCHW)
#pragma unroll
    for (int j = 0; j < 2; ++j)
#pragma unroll
      for (int f = 0; f < 8; ++f) {
        const int gy = by0 + 2 * w + (f >> 2);
        const int gx = bx0 + 16 * (f & 3) + l15;
        const int co0 = 16 * j + ch * 4;
#pragma unroll
        for (int i = 0; i < 4; ++i)
          acc[j][f][i] += hr[((size_t)(bb * 32 + co0 + i) * 512 + gy) * 512 + gx];
      }
    __syncthreads();  // tile reads done; reuse as hb buffer
    // hb -> LDS bf16, [8 rows][64 px][32ch], pitch 4096, same XOR swizzle
#pragma unroll
    for (int j = 0; j < 2; ++j)
#pragma unroll
      for (int f = 0; f < 8; ++f) {
        const int rl = 2 * w + (f >> 2);
        const int xl = 16 * (f & 3) + l15;
        const int co0 = 16 * j + ch * 4;
        unsigned short o[4];
#pragma unroll
        for (int i = 0; i < 4; ++i) o[i] = f2bf(acc[j][f][i]);
        int byt = ((rl * 4096 + xl * 64 + ((co0 >> 3) << 4)) ^ ((xl & 7) << 4)) + (co0 & 7) * 2;
        *(uint2*)(smem + byt) = *(uint2*)o;
      }
    __syncthreads();
    bfv8 whka = *(bfv8*)(smem + CTILE + 18432 + l15 * 64 + ch * 16);  // row=ct, k=ci
    float4 bv = *(const float4*)(bhk + ch * 4);
    float* S3 = (float*)outp;
#pragma unroll
    for (int f = 0; f < 8; ++f) {
      const int rl = 2 * w + (f >> 2);
      const int xl = 16 * (f & 3) + l15;
      const int byt = (rl * 4096 + xl * 64 + ch * 16) ^ ((xl & 7) << 4);
      bfv8 b = *(bfv8*)(smem + byt);
      f4v a2 = __builtin_amdgcn_mfma_f32_16x16x32_bf16(whka, b, (f4v){0.f, 0.f, 0.f, 0.f}, 0, 0, 0);
      const int gy = by0 + rl, gx = bx0 + xl;
      float o[4] = {a2[0] + bv.x, a2[1] + bv.y, a2[2] + bv.z, a2[3] + bv.w};
      *(float4*)(S3 + (size_t)bb * 4194304 + (size_t)(gy * 512 + gx) * 16 + ch * 4) = *(float4*)o;
    }
  }
}

// ---------------- f32 tiled 3x3 conv for the 128^2 lr branches (unchanged) ----
template <int N, int MODE>
__global__ __launch_bounds__(256, 4) void conv3x3_kernel(
    In3 xs, const float* __restrict__ wT, In3 rs, Out3 os)
{
  __shared__ float tile[8 * 646];
  const int bx = blockIdx.x * 16, by = blockIdx.y * 32;
  const int tn = blockIdx.z >> 1, bb = blockIdx.z & 1;
  const int tx = threadIdx.x, ty = threadIdx.y;
  const int tid = ty * 16 + tx;
  const float* xb = xs.p[tn] + (size_t)bb * 32 * N * N;

  const int r1 = tid / 18, c1 = tid % 18;
  const int gy1 = by + r1 - 1, gx1 = bx + c1 - 1;
  const int off1 = (gy1 >= 0 && gy1 < N && gx1 >= 0 && gx1 < N) ? gy1 * N + gx1 : -1;
  const int l1 = r1 * 19 + c1;
  const int s2 = tid + 256;
  const int r2 = s2 / 18, c2 = s2 % 18;
  const int gy2 = by + r2 - 1, gx2 = bx + c2 - 1;
  const int off2 = (gy2 >= 0 && gy2 < N && gx2 >= 0 && gx2 < N) ? gy2 * N + gx2 : -1;
  const int l2 = r2 * 19 + c2;
  const int s3 = tid + 512;
  const bool has3 = s3 < 612;
  const int r3 = s3 / 18, c3 = s3 % 18;
  const int gy3 = by + r3 - 1, gx3 = bx + c3 - 1;
  const int off3 = (has3 && gy3 >= 0 && gy3 < N && gx3 >= 0 && gx3 < N) ? gy3 * N + gx3 : -1;
  const int l3 = r3 * 19 + c3;

  float acc0[32], acc1[32];
#pragma unroll
  for (int co = 0; co < 32; ++co) { acc0[co] = 0.f; acc1[co] = 0.f; }

  for (int pass = 0; pass < 4; ++pass) {
    if (pass) __syncthreads();
    const int cb = pass * 8;
#pragma unroll
    for (int ci = 0; ci < 8; ++ci) {
      const float* xc = xb + (size_t)(cb + ci) * N * N;
      tile[ci * 646 + l1] = off1 >= 0 ? xc[off1] : 0.f;
      tile[ci * 646 + l2] = off2 >= 0 ? xc[off2] : 0.f;
      if (has3) tile[ci * 646 + l3] = off3 >= 0 ? xc[off3] : 0.f;
    }
    __syncthreads();

    for (int ci = 0; ci < 8; ++ci) {
      float v[4][3];
#pragma unroll
      for (int dy = 0; dy < 4; ++dy)
#pragma unroll
        for (int dx = 0; dx < 3; ++dx)
          v[dy][dx] = tile[ci * 646 + (2 * ty + dy) * 19 + (tx + dx)];
      const float* wp = wT + (size_t)(cb + ci) * 288;
#pragma unroll
      for (int co = 0; co < 32; ++co) {
        float a0 = acc0[co], a1 = acc1[co];
#pragma unroll
        for (int dy = 0; dy < 3; ++dy)
#pragma unroll
          for (int dx = 0; dx < 3; ++dx) {
            const float wv = wp[co * 9 + dy * 3 + dx];
            a0 = fmaf(v[dy][dx], wv, a0);
            a1 = fmaf(v[dy + 1][dx], wv, a1);
          }
        acc0[co] = a0; acc1[co] = a1;
      }
    }
  }

  const int gx = bx + tx, gy0 = by + 2 * ty, gy1o = gy0 + 1;
  float* ob = os.p[tn];
  const size_t pix0 = (size_t)gy0 * N + gx, pix1 = (size_t)gy1o * N + gx;
  if (MODE == 0) {
#pragma unroll
    for (int co = 0; co < 32; ++co) {
      float a = acc0[co], c = acc1[co];
      a = a > 0.f ? a : 0.1f * a;
      c = c > 0.f ? c : 0.1f * c;
      ob[((size_t)bb * 32 + co) * N * N + pix0] = a;
      ob[((size_t)bb * 32 + co) * N * N + pix1] = c;
    }
  } else {
    const float* rb = rs.p[tn] + (size_t)bb * 32 * N * N;
#pragma unroll
    for (int co = 0; co < 32; ++co) {
      ob[((size_t)bb * 32 + co) * N * N + pix0] = acc0[co] + rb[(size_t)co * N * N + pix0];
      ob[((size_t)bb * 32 + co) * N * N + pix1] = acc1[co] + rb[(size_t)co * N * N + pix1];
    }
  }
}

// ---------------- 1x1 conv 32->16, channel-last output ----------------
__global__ __launch_bounds__(256) void conv1x1_16_kernel(
    const float* __restrict__ x, const float* __restrict__ w,
    const float* __restrict__ bias, float* __restrict__ out, int NP)
{
  int p = blockIdx.x * 256 + threadIdx.x;
  int bb = p / NP, pp = p % NP;
  const float* xb = x + ((size_t)bb * 32) * NP + pp;
  float in[32];
#pragma unroll
  for (int c = 0; c < 32; ++c) in[c] = xb[(size_t)c * NP];
  float o[16];
#pragma unroll
  for (int ct = 0; ct < 16; ++ct) {
    float s = bias[ct];
#pragma unroll
    for (int c = 0; c < 32; ++c) s = fmaf(w[ct * 32 + c], in[c], s);
    o[ct] = s;
  }
  float4* op = (float4*)(out + (size_t)p * 16);
#pragma unroll
  for (int q = 0; q < 4; ++q) op[q] = ((float4*)o)[q];
}

// ---------------- NCHW -> channel-last f32 ----------------
__global__ __launch_bounds__(256) void transpose_cl_kernel(
    const float* __restrict__ x, float* __restrict__ out, int NP)
{
  int p = blockIdx.x * 256 + threadIdx.x;
  int bb = p / NP, pp = p % NP;
  const float* xb = x + ((size_t)bb * 32) * NP + pp;
  float o[32];
#pragma unroll
  for (int c = 0; c < 32; ++c) o[c] = xb[(size_t)c * NP];
  float4* op = (float4*)(out + (size_t)p * 32);
#pragma unroll
  for (int q = 0; q < 8; ++q) op[q] = ((float4*)o)[q];
}

// ---------------- fepam: one wave64 per query, lane = neighbor ----------------
__global__ __launch_bounds__(256) void fepam_kernel(
    const float* __restrict__ Qt, const float* __restrict__ St,
    const float* __restrict__ Rt, const int* __restrict__ px,
    const int* __restrict__ py, const int* __restrict__ idxflag,
    float* __restrict__ out, int Ws, int HWs)
{
  const int wid = (blockIdx.x * 256 + threadIdx.x) >> 6;
  const int lane = threadIdx.x & 63;
  const int bb = wid >> 14;
  const float* qp = Qt + (size_t)wid * 16;
  const int f = *idxflag;
  const int j = (wid * 64 + lane) << f;
  const int sidx = px[j] * Ws + py[j];

  const float* kp = St + ((size_t)bb * HWs + sidx) * 16;
  float score = 0.f;
#pragma unroll
  for (int c4 = 0; c4 < 4; ++c4) {
    float4 qv = ((const float4*)qp)[c4];
    float4 kv = ((const float4*)kp)[c4];
    score += qv.x * kv.x + qv.y * kv.y + qv.z * kv.z + qv.w * kv.w;
  }
  float m = score;
#pragma unroll
  for (int off = 32; off; off >>= 1) m = fmaxf(m, __shfl_xor(m, off));
  float e = __expf(score - m);
  float s = e;
#pragma unroll
  for (int off = 32; off; off >>= 1) s += __shfl_xor(s, off);
  float a = e / s;

  const float* vp = Rt + ((size_t)bb * HWs + sidx) * 32;
  float p[32];
#pragma unroll
  for (int c4 = 0; c4 < 8; ++c4) {
    float4 vv = ((const float4*)vp)[c4];
    p[c4 * 4 + 0] = a * vv.x; p[c4 * 4 + 1] = a * vv.y;
    p[c4 * 4 + 2] = a * vv.z; p[c4 * 4 + 3] = a * vv.w;
  }
#pragma unroll
  for (int off = 32; off; off >>= 1) {
#pragma unroll
    for (int c = 0; c < 32; ++c) p[c] += __shfl_xor(p[c], off);
  }
  if (lane == 0) {
    float4* op = (float4*)(out + (size_t)wid * 32);
#pragma unroll
    for (int q = 0; q < 8; ++q) op[q] = ((float4*)p)[q];
  }
}

// ---------------- final 1x1 over concat(b1,b2,b3,lb0) -> f32 NCHW ----------------
__global__ __launch_bounds__(256) void final_conv_kernel(
    const float* __restrict__ bt1, const float* __restrict__ bt2,
    const float* __restrict__ bt3, const float* __restrict__ lb0,
    const float* __restrict__ wf, const float* __restrict__ bfb,
    float* __restrict__ out)
{
  int p = blockIdx.x * 256 + threadIdx.x;
  int bb = p >> 14, pp = p & 16383;
  float in[128];
#pragma unroll
  for (int q = 0; q < 8; ++q) ((float4*)in)[q]        = ((const float4*)(bt1 + (size_t)p * 32))[q];
#pragma unroll
  for (int q = 0; q < 8; ++q) ((float4*)(in + 32))[q] = ((const float4*)(bt2 + (size_t)p * 32))[q];
#pragma unroll
  for (int q = 0; q < 8; ++q) ((float4*)(in + 64))[q] = ((const float4*)(bt3 + (size_t)p * 32))[q];
  const float* lp = lb0 + ((size_t)bb * 32) * 16384 + pp;
#pragma unroll
  for (int c = 0; c < 32; ++c) in[96 + c] = lp[(size_t)c * 16384];
#pragma unroll 2
  for (int co = 0; co < 32; ++co) {
    float s = bfb[co];
#pragma unroll
    for (int c = 0; c < 128; ++c) s = fmaf(wf[co * 128 + c], in[c], s);
    out[((size_t)bb * 32 + co) * 16384 + pp] = s;
  }
}

extern "C" void kernel_launch(void* const* d_in, const int* in_sizes, int n_in,
                              void* d_out, int out_size, void* d_ws, size_t ws_size,
                              hipStream_t stream)
{
  const float* lr0 = (const float*)d_in[0];
  const float* lr1 = (const float*)d_in[1];
  const float* lr2 = (const float*)d_in[2];
  const float* hr  = (const float*)d_in[3];
  const float* wl1 = (const float*)d_in[4];
  const float* wl2 = (const float*)d_in[5];
  const float* wh1 = (const float*)d_in[6];
  const float* wh2 = (const float*)d_in[7];
  const float* wq  = (const float*)d_in[8];
  const float* bq  = (const float*)d_in[9];
  const float* wk  = (const float*)d_in[10];
  const float* bk  = (const float*)d_in[11];
  const float* whk = (const float*)d_in[12];
  const float* bhk = (const float*)d_in[13];
  const float* wf  = (const float*)d_in[14];
  const float* bf  = (const float*)d_in[15];
  const int* px0 = (const int*)d_in[16];
  const int* py0 = (const int*)d_in[17];
  const int* px1 = (const int*)d_in[18];
  const int* py1 = (const int*)d_in[19];
  const int* px2 = (const int*)d_in[20];
  const int* py2 = (const int*)d_in[21];
  float* out = (float*)d_out;
  float* ws = (float*)d_ws;

  float* S3T = ws;
  float* R3T = ws + 8388608;
  unsigned short* HRC = (unsigned short*)(ws + 16777216);  // dead before R3T write
  unsigned short* YC  = (unsigned short*)(ws + 25165824);  // dead before LB*/QT/.. writes
  float* LB0 = ws + 25165824;
  float* LB1 = ws + 26214400;
  float* LB2 = ws + 27262976;
  float* QT  = ws + 29360128;
  float* S1T = ws + 29884416;
  float* S2T = ws + 30408704;
  float* R1T = ws + 30932992;
  float* R2T = ws + 31981568;
  float* BT1 = ws + 33030144;
  float* BT2 = ws + 34078720;
  float* BT3 = ws + 35127296;
  float* WTL1 = ws + 36175872;
  float* WTL2 = ws + 36185088;
  unsigned short* WB1  = (unsigned short*)(ws + 36194304);
  unsigned short* WB2  = (unsigned short*)(ws + 36198912);
  unsigned short* WHKB = (unsigned short*)(ws + 36203520);
  int* IDXFLAG = (int*)(ws + 36203776);

  dim3 blk(16, 16);

  // prep
  idx_detect_kernel<<<1, 256, 0, stream>>>(px0, IDXFLAG);
  wtrans_kernel<<<dim3(36, 2), 256, 0, stream>>>(wl1, wl2, WTL1, WTL2);
  wconv_bf16_kernel<<<dim3(36, 3), 256, 0, stream>>>(wh1, wh2, whk, WB1, WB2, WHKB);
  hrc_kernel<<<2048, 256, 0, stream>>>(hr, HRC);

  // hr branch: MFMA convs; S3 fused; hb never materialized
  conv_mfma_kernel<0><<<dim3(8, 64, 2), 256, 0, stream>>>(HRC, WB1, nullptr, nullptr, nullptr, YC);
  conv_mfma_kernel<2><<<dim3(8, 64, 2), 256, 0, stream>>>(YC, WB2, hr, WHKB, bhk, S3T);
  transpose_cl_kernel<<<2048, 256, 0, stream>>>(hr, R3T, 262144);

  // lr branches, batched over 3 tensors (shared f32 weights)
  In3 none{};
  conv3x3_kernel<128, 0><<<dim3(8, 4, 6), blk, 0, stream>>>(
      In3{{lr0, lr1, lr2}}, WTL1, none, Out3{{BT1, BT2, BT3}});
  conv3x3_kernel<128, 1><<<dim3(8, 4, 6), blk, 0, stream>>>(
      In3{{BT1, BT2, BT3}}, WTL2, In3{{lr0, lr1, lr2}}, Out3{{LB0, LB1, LB2}});

  // projections + value transposes
  conv1x1_16_kernel<<<128, 256, 0, stream>>>(LB0, wq, bq, QT, 16384);
  conv1x1_16_kernel<<<128, 256, 0, stream>>>(LB1, wk, bk, S1T, 16384);
  conv1x1_16_kernel<<<128, 256, 0, stream>>>(LB2, wk, bk, S2T, 16384);
  transpose_cl_kernel<<<128, 256, 0, stream>>>(lr1, R1T, 16384);
  transpose_cl_kernel<<<128, 256, 0, stream>>>(lr2, R2T, 16384);

  // gather attention
  fepam_kernel<<<8192, 256, 0, stream>>>(QT, S1T, R1T, px0, py0, IDXFLAG, BT1, 128, 16384);
  fepam_kernel<<<8192, 256, 0, stream>>>(QT, S2T, R2T, px1, py1, IDXFLAG, BT2, 128, 16384);
  fepam_kernel<<<8192, 256, 0, stream>>>(QT, S3T, R3T, px2, py2, IDXFLAG, BT3, 512, 262144);

  // final fuse
  final_conv_kernel<<<128, 256, 0, stream>>>(BT1, BT2, BT3, LB0, wf, bf, out);
}

// Round 7
// 393.445 us; speedup vs baseline: 4.6117x; 1.8724x over previous
//
#include <hip/hip_runtime.h>
#include <hip/hip_bf16.h>

typedef short bfv8 __attribute__((ext_vector_type(8)));
typedef float f4v __attribute__((ext_vector_type(4)));

static __device__ __forceinline__ unsigned short f2bf(float f) {
  unsigned u = __float_as_uint(f);
  unsigned r = (u + 0x7FFFu + ((u >> 16) & 1u)) >> 16;
  return (unsigned short)r;
}

// Workspace (float offsets):
// S3T (2,512,512,16) f32 @0..8388608
// YC  (hr intermediate bf16 CL) @8388608..16777216
//   aliased lr temporaries (all dead before YC is written):
//   YLC bf16 @8388608 (1.57M fl) | R0T @9961472 | R1T @11010048 | R2T @12058624
//   LRC bf16 @13107200..14680064
// HRC (hr bf16 CL) @16777216..25165824
// LB0/1/2 f32 CL @25165824/26214400/27262976
// QT/S1T/S2T f32 CL16 @29360128/29884416/30408704
// BT1/2/3 f32 CL32 @33030144/34078720/35127296
// WBL1/WBL2/WBH1/WBH2 bf16 @36175872/+4608/+9216/+13824 ; WHKB @+18432 ; IDXFLAG @+18720

struct B3  { const unsigned short* p[3]; };
struct F3  { const float* p[3]; };
struct OB3 { unsigned short* p[3]; };
struct OF3 { float* p[3]; };

// ---------------- index-dtype probe ----------------
__global__ void idx_detect_kernel(const int* __restrict__ px, int* __restrict__ flag) {
  __shared__ int s;
  if (threadIdx.x == 0) s = 0;
  __syncthreads();
  int v = px[2 * threadIdx.x + 1];
  if (v != 0) atomicOr(&s, 1);
  __syncthreads();
  if (threadIdx.x == 0) *flag = (s == 0) ? 1 : 0;  // 1 => int64, 0 => int32
}

// ---------------- bf16 weight prep: [co][ci][3][3] -> [tap][co][ci]; y==4: whk ----
__global__ __launch_bounds__(256) void wconv_bf16_kernel(
    const float* __restrict__ wl1, const float* __restrict__ wl2,
    const float* __restrict__ wh1, const float* __restrict__ wh2,
    const float* __restrict__ whk,
    unsigned short* __restrict__ ol1, unsigned short* __restrict__ ol2,
    unsigned short* __restrict__ oh1, unsigned short* __restrict__ oh2,
    unsigned short* __restrict__ ok)
{
  int i = blockIdx.x * 256 + threadIdx.x;
  int y = blockIdx.y;
  if (y < 4) {
    const float* w = y == 0 ? wl1 : y == 1 ? wl2 : y == 2 ? wh1 : wh2;
    unsigned short* o = y == 0 ? ol1 : y == 1 ? ol2 : y == 2 ? oh1 : oh2;
    if (i < 9216) {
      int t = i / 1024, rem = i % 1024, co = rem >> 5, ci = rem & 31;
      o[i] = f2bf(w[(co * 32 + ci) * 9 + t]);
    }
  } else if (i < 512) {
    ok[i] = f2bf(whk[i]);
  }
}

// ---------------- hr NCHW f32 -> channel-last bf16 ----------------
__global__ __launch_bounds__(256) void hrc_kernel(
    const float* __restrict__ x, unsigned short* __restrict__ o)
{
  int p = blockIdx.x * 256 + threadIdx.x;  // [0, 524288)
  int bb = p >> 18, pp = p & 262143;
  const float* xb = x + ((size_t)bb * 32) * 262144 + pp;
  unsigned short v[32];
#pragma unroll
  for (int c = 0; c < 32; ++c) v[c] = f2bf(xb[(size_t)c * 262144]);
  uint4* op = (uint4*)(o + (size_t)p * 32);
#pragma unroll
  for (int q = 0; q < 4; ++q) op[q] = ((uint4*)v)[q];
}

// ---------------- lr prep: NCHW f32 -> CL f32 (R*T) + CL bf16 (LRC) ----------------
__global__ __launch_bounds__(256) void lrprep_kernel(
    F3 xs, OF3 of, OB3 ob)
{
  int tn = blockIdx.y;
  int p = blockIdx.x * 256 + threadIdx.x;  // [0, 32768)
  int bb = p >> 14, pp = p & 16383;
  const float* xb = xs.p[tn] + ((size_t)bb * 32) * 16384 + pp;
  float o[32];
  unsigned short v[32];
#pragma unroll
  for (int c = 0; c < 32; ++c) { o[c] = xb[(size_t)c * 16384]; v[c] = f2bf(o[c]); }
  float4* op = (float4*)(of.p[tn] + (size_t)p * 32);
#pragma unroll
  for (int q = 0; q < 8; ++q) op[q] = ((float4*)o)[q];
  uint4* bp = (uint4*)(ob.p[tn] + (size_t)p * 32);
#pragma unroll
  for (int q = 0; q < 4; ++q) bp[q] = ((uint4*)v)[q];
}

// ---------------- MFMA 3x3 conv, bf16 channel-last ----------------
// Block: 8 rows x 64 cols, 4 waves; wave w: rows 2w..2w+1 (128 px x 32 co).
// MODE 0: outb = lrelu(conv)                      (bf16 CL)
// MODE 1: outf = conv + res (f32 CL)              (f32 CL)
// MODE 2: hb = conv + hrres (f32 NCHW); outf = whk*hb + bhk (f32 CL 16ch)
#define CTILE 42240  // 10 rows x 66 px x 64B
template <int N, int MODE>
__global__ __launch_bounds__(256, 2) void conv_mfma_kernel(
    B3 xs, const unsigned short* __restrict__ WB, F3 res,
    const float* __restrict__ hrres, const unsigned short* __restrict__ WHKB,
    const float* __restrict__ bhk, OB3 outb, OF3 outf)
{
  __shared__ uint4 smem_[3856];  // 61696 B: tile 42240 | conv W 18432 | whk 1024
  unsigned char* smem = (unsigned char*)smem_;
  const int NN = N * N;
  const int bx0 = blockIdx.x * 64, by0 = blockIdx.y * 8;
  const int tn = (N == 512) ? 0 : (blockIdx.z >> 1);
  const int bb = (N == 512) ? blockIdx.z : (blockIdx.z & 1);
  const int tid = threadIdx.x;
  const int w = tid >> 6, lane = tid & 63;
  const int l15 = lane & 15, ch = lane >> 4;

  // stage input tile (rows by0-1..by0+8, px bx0-1..bx0+64, 32ch bf16), XOR-swizzled
  const unsigned short* Xb = xs.p[tn] + (size_t)bb * NN * 32;
  for (int g = tid; g < 2640; g += 256) {
    int row = g / 264, rem = g - row * 264;
    int px = rem >> 2, c4 = rem & 3;
    int gy = by0 + row - 1, gx = bx0 + px - 1;
    uint4 v = {0u, 0u, 0u, 0u};
    if (gy >= 0 && gy < N && gx >= 0 && gx < N)
      v = *(const uint4*)(Xb + (size_t)(gy * N + gx) * 32 + c4 * 8);
    int byt = (row * 4224 + px * 64 + c4 * 16) ^ ((px & 7) << 4);
    *(uint4*)(smem + byt) = v;
  }
  for (int g = tid; g < 1152; g += 256)
    *(uint4*)(smem + CTILE + g * 16) = *(const uint4*)(WB + g * 8);
  if (MODE == 2) {
    if (tid < 64)
      *(uint4*)(smem + CTILE + 18432 + tid * 16) = *(const uint4*)(WHKB + tid * 8);
  }
  __syncthreads();

  // weight A-fragments (row = co, k = ci)
  bfv8 wa[9][2];
#pragma unroll
  for (int t = 0; t < 9; ++t)
#pragma unroll
    for (int j = 0; j < 2; ++j)
      wa[t][j] = *(bfv8*)(smem + CTILE + t * 2048 + (16 * j + l15) * 64 + ch * 16);

  f4v acc[2][8];
#pragma unroll
  for (int j = 0; j < 2; ++j)
#pragma unroll
    for (int f = 0; f < 8; ++f) acc[j][f] = (f4v){0.f, 0.f, 0.f, 0.f};

#pragma unroll
  for (int dy = 0; dy < 3; ++dy)
#pragma unroll
    for (int dx = 0; dx < 3; ++dx)
#pragma unroll
      for (int f = 0; f < 8; ++f) {
        const int hrow = 2 * w + (f >> 2) + dy;
        const int xh = 16 * (f & 3) + l15 + dx;
        const int byt = (hrow * 4224 + xh * 64 + ch * 16) ^ ((xh & 7) << 4);
        bfv8 b = *(bfv8*)(smem + byt);
        acc[0][f] = __builtin_amdgcn_mfma_f32_16x16x32_bf16(wa[dy * 3 + dx][0], b, acc[0][f], 0, 0, 0);
        acc[1][f] = __builtin_amdgcn_mfma_f32_16x16x32_bf16(wa[dy * 3 + dx][1], b, acc[1][f], 0, 0, 0);
      }

  // D layout: col(px) = l15, row(co within frag) = ch*4+i
  if (MODE == 0) {
    unsigned short* ob = outb.p[tn] + (size_t)bb * NN * 32;
#pragma unroll
    for (int j = 0; j < 2; ++j)
#pragma unroll
      for (int f = 0; f < 8; ++f) {
        const int gy = by0 + 2 * w + (f >> 2);
        const int gx = bx0 + 16 * (f & 3) + l15;
        const int co0 = 16 * j + ch * 4;
        unsigned short o[4];
#pragma unroll
        for (int i = 0; i < 4; ++i) {
          float a = acc[j][f][i];
          a = a > 0.f ? a : 0.1f * a;
          o[i] = f2bf(a);
        }
        *(uint2*)(ob + (size_t)(gy * N + gx) * 32 + co0) = *(uint2*)o;
      }
  } else if (MODE == 1) {
    const float* rb = res.p[tn] + (size_t)bb * NN * 32;
    float* ob = outf.p[tn] + (size_t)bb * NN * 32;
#pragma unroll
    for (int j = 0; j < 2; ++j)
#pragma unroll
      for (int f = 0; f < 8; ++f) {
        const int gy = by0 + 2 * w + (f >> 2);
        const int gx = bx0 + 16 * (f & 3) + l15;
        const int co0 = 16 * j + ch * 4;
        const size_t base = (size_t)(gy * N + gx) * 32 + co0;
        float4 r = *(const float4*)(rb + base);
        float o[4] = {acc[j][f][0] + r.x, acc[j][f][1] + r.y,
                      acc[j][f][2] + r.z, acc[j][f][3] + r.w};
        *(float4*)(ob + base) = *(float4*)o;
      }
  } else {
    // residual add (hrres is f32 NCHW)
#pragma unroll
    for (int j = 0; j < 2; ++j)
#pragma unroll
      for (int f = 0; f < 8; ++f) {
        const int gy = by0 + 2 * w + (f >> 2);
        const int gx = bx0 + 16 * (f & 3) + l15;
        const int co0 = 16 * j + ch * 4;
#pragma unroll
        for (int i = 0; i < 4; ++i)
          acc[j][f][i] += hrres[((size_t)(bb * 32 + co0 + i) * N + gy) * N + gx];
      }
    __syncthreads();  // tile reads done; reuse LDS as hb buffer
#pragma unroll
    for (int j = 0; j < 2; ++j)
#pragma unroll
      for (int f = 0; f < 8; ++f) {
        const int rl = 2 * w + (f >> 2);
        const int xl = 16 * (f & 3) + l15;
        const int co0 = 16 * j + ch * 4;
        unsigned short o[4];
#pragma unroll
        for (int i = 0; i < 4; ++i) o[i] = f2bf(acc[j][f][i]);
        int byt = ((rl * 4096 + xl * 64 + ((co0 >> 3) << 4)) ^ ((xl & 7) << 4)) + (co0 & 7) * 2;
        *(uint2*)(smem + byt) = *(uint2*)o;
      }
    __syncthreads();
    bfv8 whka = *(bfv8*)(smem + CTILE + 18432 + l15 * 64 + ch * 16);  // row=ct, k=ci
    float4 bv = *(const float4*)(bhk + ch * 4);
    float* S3 = outf.p[0];
#pragma unroll
    for (int f = 0; f < 8; ++f) {
      const int rl = 2 * w + (f >> 2);
      const int xl = 16 * (f & 3) + l15;
      const int byt = (rl * 4096 + xl * 64 + ch * 16) ^ ((xl & 7) << 4);
      bfv8 b = *(bfv8*)(smem + byt);
      f4v a2 = __builtin_amdgcn_mfma_f32_16x16x32_bf16(whka, b, (f4v){0.f, 0.f, 0.f, 0.f}, 0, 0, 0);
      const int gy = by0 + rl, gx = bx0 + xl;
      float o[4] = {a2[0] + bv.x, a2[1] + bv.y, a2[2] + bv.z, a2[3] + bv.w};
      *(float4*)(S3 + (size_t)bb * ((size_t)NN * 16) + (size_t)(gy * N + gx) * 16 + ch * 4) = *(float4*)o;
    }
  }
}

// ---------------- 1x1 conv 32->16, CL in / CL out, batched over 3 ----------------
__global__ __launch_bounds__(256) void conv1x1_16_kernel(
    F3 xs, const float* __restrict__ wq, const float* __restrict__ bq,
    const float* __restrict__ wk, const float* __restrict__ bk, OF3 os)
{
  int tn = blockIdx.y;
  const float* w = tn == 0 ? wq : wk;
  const float* bias = tn == 0 ? bq : bk;
  int p = blockIdx.x * 256 + threadIdx.x;  // [0, 32768)
  const float* xb = xs.p[tn] + (size_t)p * 32;
  float in[32];
#pragma unroll
  for (int q = 0; q < 8; ++q) ((float4*)in)[q] = ((const float4*)xb)[q];
  float o[16];
#pragma unroll
  for (int ct = 0; ct < 16; ++ct) {
    float s = bias[ct];
#pragma unroll
    for (int c = 0; c < 32; ++c) s = fmaf(w[ct * 32 + c], in[c], s);
    o[ct] = s;
  }
  float4* op = (float4*)(os.p[tn] + (size_t)p * 16);
#pragma unroll
  for (int q = 0; q < 4; ++q) op[q] = ((float4*)o)[q];
}

// ---------------- fepam: one wave64 per query, lane = neighbor; V is bf16 CL ----
__global__ __launch_bounds__(256) void fepam_kernel(
    const float* __restrict__ Qt, const float* __restrict__ St,
    const unsigned short* __restrict__ Rt, const int* __restrict__ px,
    const int* __restrict__ py, const int* __restrict__ idxflag,
    float* __restrict__ out, int Ws, int HWs)
{
  const int wid = (blockIdx.x * 256 + threadIdx.x) >> 6;
  const int lane = threadIdx.x & 63;
  const int bb = wid >> 14;
  const float* qp = Qt + (size_t)wid * 16;
  const int f = *idxflag;
  const int j = (wid * 64 + lane) << f;
  const int sidx = px[j] * Ws + py[j];

  const float* kp = St + ((size_t)bb * HWs + sidx) * 16;
  float score = 0.f;
#pragma unroll
  for (int c4 = 0; c4 < 4; ++c4) {
    float4 qv = ((const float4*)qp)[c4];
    float4 kv = ((const float4*)kp)[c4];
    score += qv.x * kv.x + qv.y * kv.y + qv.z * kv.z + qv.w * kv.w;
  }
  float m = score;
#pragma unroll
  for (int off = 32; off; off >>= 1) m = fmaxf(m, __shfl_xor(m, off));
  float e = __expf(score - m);
  float s = e;
#pragma unroll
  for (int off = 32; off; off >>= 1) s += __shfl_xor(s, off);
  float a = e / s;

  const unsigned short* vp = Rt + ((size_t)bb * HWs + sidx) * 32;
  unsigned vv[16];
#pragma unroll
  for (int q = 0; q < 4; ++q) ((uint4*)vv)[q] = ((const uint4*)vp)[q];
  float p[32];
#pragma unroll
  for (int i = 0; i < 16; ++i) {
    p[2 * i]     = a * __uint_as_float(vv[i] << 16);
    p[2 * i + 1] = a * __uint_as_float(vv[i] & 0xFFFF0000u);
  }
#pragma unroll
  for (int off = 32; off; off >>= 1) {
#pragma unroll
    for (int c = 0; c < 32; ++c) p[c] += __shfl_xor(p[c], off);
  }
  if (lane == 0) {
    float4* op = (float4*)(out + (size_t)wid * 32);
#pragma unroll
    for (int q = 0; q < 8; ++q) op[q] = ((float4*)p)[q];
  }
}

// ---------------- final 1x1 over concat(b1,b2,b3,lb0 CL) -> f32 NCHW ----------------
__global__ __launch_bounds__(256) void final_conv_kernel(
    const float* __restrict__ bt1, const float* __restrict__ bt2,
    const float* __restrict__ bt3, const float* __restrict__ lb0,
    const float* __restrict__ wf, const float* __restrict__ bfb,
    float* __restrict__ out)
{
  int p = blockIdx.x * 256 + threadIdx.x;
  int bb = p >> 14, pp = p & 16383;
  float in[128];
#pragma unroll
  for (int q = 0; q < 8; ++q) ((float4*)in)[q]        = ((const float4*)(bt1 + (size_t)p * 32))[q];
#pragma unroll
  for (int q = 0; q < 8; ++q) ((float4*)(in + 32))[q] = ((const float4*)(bt2 + (size_t)p * 32))[q];
#pragma unroll
  for (int q = 0; q < 8; ++q) ((float4*)(in + 64))[q] = ((const float4*)(bt3 + (size_t)p * 32))[q];
#pragma unroll
  for (int q = 0; q < 8; ++q) ((float4*)(in + 96))[q] = ((const float4*)(lb0 + (size_t)p * 32))[q];
#pragma unroll 2
  for (int co = 0; co < 32; ++co) {
    float s = bfb[co];
#pragma unroll
    for (int c = 0; c < 128; ++c) s = fmaf(wf[co * 128 + c], in[c], s);
    out[((size_t)bb * 32 + co) * 16384 + pp] = s;
  }
}

extern "C" void kernel_launch(void* const* d_in, const int* in_sizes, int n_in,
                              void* d_out, int out_size, void* d_ws, size_t ws_size,
                              hipStream_t stream)
{
  const float* lr0 = (const float*)d_in[0];
  const float* lr1 = (const float*)d_in[1];
  const float* lr2 = (const float*)d_in[2];
  const float* hr  = (const float*)d_in[3];
  const float* wl1 = (const float*)d_in[4];
  const float* wl2 = (const float*)d_in[5];
  const float* wh1 = (const float*)d_in[6];
  const float* wh2 = (const float*)d_in[7];
  const float* wq  = (const float*)d_in[8];
  const float* bq  = (const float*)d_in[9];
  const float* wk  = (const float*)d_in[10];
  const float* bk  = (const float*)d_in[11];
  const float* whk = (const float*)d_in[12];
  const float* bhk = (const float*)d_in[13];
  const float* wf  = (const float*)d_in[14];
  const float* bf  = (const float*)d_in[15];
  const int* px0 = (const int*)d_in[16];
  const int* py0 = (const int*)d_in[17];
  const int* px1 = (const int*)d_in[18];
  const int* py1 = (const int*)d_in[19];
  const int* px2 = (const int*)d_in[20];
  const int* py2 = (const int*)d_in[21];
  float* out = (float*)d_out;
  float* ws = (float*)d_ws;

  float* S3T = ws;
  unsigned short* YC  = (unsigned short*)(ws + 8388608);   // hr intermediate
  unsigned short* YLC = (unsigned short*)(ws + 8388608);   // lr intermediate (dead before YC)
  float* R0T = ws + 9961472;
  float* R1T = ws + 11010048;
  float* R2T = ws + 12058624;
  unsigned short* LRC = (unsigned short*)(ws + 13107200);  // bf16 CL lr0/1/2 (dead before YC)
  unsigned short* HRC = (unsigned short*)(ws + 16777216);
  float* LB0 = ws + 25165824;
  float* LB1 = ws + 26214400;
  float* LB2 = ws + 27262976;
  float* QT  = ws + 29360128;
  float* S1T = ws + 29884416;
  float* S2T = ws + 30408704;
  float* BT1 = ws + 33030144;
  float* BT2 = ws + 34078720;
  float* BT3 = ws + 35127296;
  unsigned short* WBL1 = (unsigned short*)(ws + 36175872);
  unsigned short* WBL2 = (unsigned short*)(ws + 36180480);
  unsigned short* WBH1 = (unsigned short*)(ws + 36185088);
  unsigned short* WBH2 = (unsigned short*)(ws + 36189696);
  unsigned short* WHKB = (unsigned short*)(ws + 36194304);
  int* IDXFLAG = (int*)(ws + 36194560);

  unsigned short* LRC0 = LRC;
  unsigned short* LRC1 = LRC + 1048576;
  unsigned short* LRC2 = LRC + 2097152;
  unsigned short* YLC0 = YLC;
  unsigned short* YLC1 = YLC + 1048576;
  unsigned short* YLC2 = YLC + 2097152;

  B3 none{};
  F3 fnone{};
  OB3 obnone{};
  OF3 ofnone{};

  // prep
  idx_detect_kernel<<<1, 256, 0, stream>>>(px0, IDXFLAG);
  wconv_bf16_kernel<<<dim3(36, 5), 256, 0, stream>>>(wl1, wl2, wh1, wh2, whk,
                                                     WBL1, WBL2, WBH1, WBH2, WHKB);
  lrprep_kernel<<<dim3(128, 3), 256, 0, stream>>>(
      F3{{lr0, lr1, lr2}}, OF3{{R0T, R1T, R2T}}, OB3{{LRC0, LRC1, LRC2}});
  hrc_kernel<<<2048, 256, 0, stream>>>(hr, HRC);

  // lr resb via MFMA (batched 3 tensors)
  conv_mfma_kernel<128, 0><<<dim3(2, 16, 6), 256, 0, stream>>>(
      B3{{LRC0, LRC1, LRC2}}, WBL1, fnone, nullptr, nullptr, nullptr,
      OB3{{YLC0, YLC1, YLC2}}, ofnone);
  conv_mfma_kernel<128, 1><<<dim3(2, 16, 6), 256, 0, stream>>>(
      B3{{YLC0, YLC1, YLC2}}, WBL2, F3{{R0T, R1T, R2T}}, nullptr, nullptr, nullptr,
      obnone, OF3{{LB0, LB1, LB2}});

  // projections (CL in / CL out), batched
  conv1x1_16_kernel<<<dim3(128, 3), 256, 0, stream>>>(
      F3{{LB0, LB1, LB2}}, wq, bq, wk, bk, OF3{{QT, S1T, S2T}});

  // fepam 1/2 (V from LRC bf16) — before YC overwrites the lr temp region
  fepam_kernel<<<8192, 256, 0, stream>>>(QT, S1T, LRC1, px0, py0, IDXFLAG, BT1, 128, 16384);
  fepam_kernel<<<8192, 256, 0, stream>>>(QT, S2T, LRC2, px1, py1, IDXFLAG, BT2, 128, 16384);

  // hr resb via MFMA; S3 fused; hb never materialized
  conv_mfma_kernel<512, 0><<<dim3(8, 64, 2), 256, 0, stream>>>(
      B3{{HRC}}, WBH1, fnone, nullptr, nullptr, nullptr, OB3{{YC}}, ofnone);
  conv_mfma_kernel<512, 2><<<dim3(8, 64, 2), 256, 0, stream>>>(
      B3{{YC}}, WBH2, fnone, hr, WHKB, bhk, obnone, OF3{{S3T}});

  // fepam 3 (V from HRC bf16)
  fepam_kernel<<<8192, 256, 0, stream>>>(QT, S3T, HRC, px2, py2, IDXFLAG, BT3, 512, 262144);

  // final fuse
  final_conv_kernel<<<128, 256, 0, stream>>>(BT1, BT2, BT3, LB0, wf, bf, out);
}

// Round 8
// 317.661 us; speedup vs baseline: 5.7120x; 1.2386x over previous
//
#include <hip/hip_runtime.h>
#include <hip/hip_bf16.h>

typedef short bfv8 __attribute__((ext_vector_type(8)));
typedef float f4v __attribute__((ext_vector_type(4)));

static __device__ __forceinline__ unsigned short f2bf(float f) {
  unsigned u = __float_as_uint(f);
  unsigned r = (u + 0x7FFFu + ((u >> 16) & 1u)) >> 16;
  return (unsigned short)r;
}

// Workspace (float offsets):
// S3B bf16 (2,512,512,16) @0..4194304
// YC  (hr intermediate bf16 CL) @8388608..16777216
//   aliased lr temporaries (dead before YC written):
//   YLC bf16 @8388608 | R0T @9961472 | R1T @11010048 | R2T @12058624 | LRC bf16 @13107200
// HRC (hr bf16 CL) @16777216..25165824
// LB0/1/2 f32 CL @25165824/26214400/27262976
// QT f32 CL16 @29360128 ; S1B/S2B bf16 CL16 @29884416/30408704
// BT1/2/3 f32 CL32 @33030144/34078720/35127296
// WBL1/WBL2/WBH1/WBH2 bf16 @36175872/+4608/+9216/+13824 ; WHKB @+18432 ; IDXFLAG @+18720

struct B3  { const unsigned short* p[3]; };
struct F3  { const float* p[3]; };
struct OB3 { unsigned short* p[3]; };
struct OF3 { float* p[3]; };

// ---------------- index-dtype probe ----------------
__global__ void idx_detect_kernel(const int* __restrict__ px, int* __restrict__ flag) {
  __shared__ int s;
  if (threadIdx.x == 0) s = 0;
  __syncthreads();
  int v = px[2 * threadIdx.x + 1];
  if (v != 0) atomicOr(&s, 1);
  __syncthreads();
  if (threadIdx.x == 0) *flag = (s == 0) ? 1 : 0;  // 1 => int64, 0 => int32
}

// ---------------- bf16 weight prep: [co][ci][3][3] -> [tap][co][ci]; y==4: whk ----
__global__ __launch_bounds__(256) void wconv_bf16_kernel(
    const float* __restrict__ wl1, const float* __restrict__ wl2,
    const float* __restrict__ wh1, const float* __restrict__ wh2,
    const float* __restrict__ whk,
    unsigned short* __restrict__ ol1, unsigned short* __restrict__ ol2,
    unsigned short* __restrict__ oh1, unsigned short* __restrict__ oh2,
    unsigned short* __restrict__ ok)
{
  int i = blockIdx.x * 256 + threadIdx.x;
  int y = blockIdx.y;
  if (y < 4) {
    const float* w = y == 0 ? wl1 : y == 1 ? wl2 : y == 2 ? wh1 : wh2;
    unsigned short* o = y == 0 ? ol1 : y == 1 ? ol2 : y == 2 ? oh1 : oh2;
    if (i < 9216) {
      int t = i / 1024, rem = i % 1024, co = rem >> 5, ci = rem & 31;
      o[i] = f2bf(w[(co * 32 + ci) * 9 + t]);
    }
  } else if (i < 512) {
    ok[i] = f2bf(whk[i]);
  }
}

// ---------------- hr NCHW f32 -> channel-last bf16 ----------------
__global__ __launch_bounds__(256) void hrc_kernel(
    const float* __restrict__ x, unsigned short* __restrict__ o)
{
  int p = blockIdx.x * 256 + threadIdx.x;  // [0, 524288)
  int bb = p >> 18, pp = p & 262143;
  const float* xb = x + ((size_t)bb * 32) * 262144 + pp;
  unsigned short v[32];
#pragma unroll
  for (int c = 0; c < 32; ++c) v[c] = f2bf(xb[(size_t)c * 262144]);
  uint4* op = (uint4*)(o + (size_t)p * 32);
#pragma unroll
  for (int q = 0; q < 4; ++q) op[q] = ((uint4*)v)[q];
}

// ---------------- lr prep: NCHW f32 -> CL f32 (R*T) + CL bf16 (LRC) ----------------
__global__ __launch_bounds__(256) void lrprep_kernel(
    F3 xs, OF3 of, OB3 ob)
{
  int tn = blockIdx.y;
  int p = blockIdx.x * 256 + threadIdx.x;  // [0, 32768)
  int bb = p >> 14, pp = p & 16383;
  const float* xb = xs.p[tn] + ((size_t)bb * 32) * 16384 + pp;
  float o[32];
  unsigned short v[32];
#pragma unroll
  for (int c = 0; c < 32; ++c) { o[c] = xb[(size_t)c * 16384]; v[c] = f2bf(o[c]); }
  float4* op = (float4*)(of.p[tn] + (size_t)p * 32);
#pragma unroll
  for (int q = 0; q < 8; ++q) op[q] = ((float4*)o)[q];
  uint4* bp = (uint4*)(ob.p[tn] + (size_t)p * 32);
#pragma unroll
  for (int q = 0; q < 4; ++q) bp[q] = ((uint4*)v)[q];
}

// ---------------- MFMA 3x3 conv, bf16 channel-last ----------------
// Block: 8 rows x 64 cols, 4 waves; wave w: rows 2w..2w+1 (128 px x 32 co).
// MODE 0: outb = lrelu(conv)                (bf16 CL)
// MODE 1: outf = conv + res (f32 CL)        (f32 CL)
// MODE 2: hb = conv + hrres (f32 NCHW); outb.p[0] = bf16(whk*hb + bhk) (CL 16ch)
#define CTILE 42240  // 10 rows x 66 px x 64B
template <int N, int MODE>
__global__ __launch_bounds__(256, 2) void conv_mfma_kernel(
    B3 xs, const unsigned short* __restrict__ WB, F3 res,
    const float* __restrict__ hrres, const unsigned short* __restrict__ WHKB,
    const float* __restrict__ bhk, OB3 outb, OF3 outf)
{
  __shared__ uint4 smem_[3856];  // 61696 B: tile 42240 | conv W 18432 | whk 1024
  unsigned char* smem = (unsigned char*)smem_;
  const int NN = N * N;
  const int bx0 = blockIdx.x * 64, by0 = blockIdx.y * 8;
  const int tn = (N == 512) ? 0 : (blockIdx.z >> 1);
  const int bb = (N == 512) ? blockIdx.z : (blockIdx.z & 1);
  const int tid = threadIdx.x;
  const int w = tid >> 6, lane = tid & 63;
  const int l15 = lane & 15, ch = lane >> 4;

  // stage input tile (rows by0-1..by0+8, px bx0-1..bx0+64, 32ch bf16), XOR-swizzled
  const unsigned short* Xb = xs.p[tn] + (size_t)bb * NN * 32;
  for (int g = tid; g < 2640; g += 256) {
    int row = g / 264, rem = g - row * 264;
    int px = rem >> 2, c4 = rem & 3;
    int gy = by0 + row - 1, gx = bx0 + px - 1;
    uint4 v = {0u, 0u, 0u, 0u};
    if (gy >= 0 && gy < N && gx >= 0 && gx < N)
      v = *(const uint4*)(Xb + (size_t)(gy * N + gx) * 32 + c4 * 8);
    int byt = (row * 4224 + px * 64 + c4 * 16) ^ ((px & 7) << 4);
    *(uint4*)(smem + byt) = v;
  }
  for (int g = tid; g < 1152; g += 256)
    *(uint4*)(smem + CTILE + g * 16) = *(const uint4*)(WB + g * 8);
  if (MODE == 2) {
    if (tid < 64)
      *(uint4*)(smem + CTILE + 18432 + tid * 16) = *(const uint4*)(WHKB + tid * 8);
  }
  __syncthreads();

  // weight A-fragments (row = co, k = ci)
  bfv8 wa[9][2];
#pragma unroll
  for (int t = 0; t < 9; ++t)
#pragma unroll
    for (int j = 0; j < 2; ++j)
      wa[t][j] = *(bfv8*)(smem + CTILE + t * 2048 + (16 * j + l15) * 64 + ch * 16);

  f4v acc[2][8];
#pragma unroll
  for (int j = 0; j < 2; ++j)
#pragma unroll
    for (int f = 0; f < 8; ++f) acc[j][f] = (f4v){0.f, 0.f, 0.f, 0.f};

#pragma unroll
  for (int dy = 0; dy < 3; ++dy)
#pragma unroll
    for (int dx = 0; dx < 3; ++dx)
#pragma unroll
      for (int f = 0; f < 8; ++f) {
        const int hrow = 2 * w + (f >> 2) + dy;
        const int xh = 16 * (f & 3) + l15 + dx;
        const int byt = (hrow * 4224 + xh * 64 + ch * 16) ^ ((xh & 7) << 4);
        bfv8 b = *(bfv8*)(smem + byt);
        acc[0][f] = __builtin_amdgcn_mfma_f32_16x16x32_bf16(wa[dy * 3 + dx][0], b, acc[0][f], 0, 0, 0);
        acc[1][f] = __builtin_amdgcn_mfma_f32_16x16x32_bf16(wa[dy * 3 + dx][1], b, acc[1][f], 0, 0, 0);
      }

  // D layout: col(px) = l15, row(co within frag) = ch*4+i
  if (MODE == 0) {
    unsigned short* ob = outb.p[tn] + (size_t)bb * NN * 32;
#pragma unroll
    for (int j = 0; j < 2; ++j)
#pragma unroll
      for (int f = 0; f < 8; ++f) {
        const int gy = by0 + 2 * w + (f >> 2);
        const int gx = bx0 + 16 * (f & 3) + l15;
        const int co0 = 16 * j + ch * 4;
        unsigned short o[4];
#pragma unroll
        for (int i = 0; i < 4; ++i) {
          float a = acc[j][f][i];
          a = a > 0.f ? a : 0.1f * a;
          o[i] = f2bf(a);
        }
        *(uint2*)(ob + (size_t)(gy * N + gx) * 32 + co0) = *(uint2*)o;
      }
  } else if (MODE == 1) {
    const float* rb = res.p[tn] + (size_t)bb * NN * 32;
    float* ob = outf.p[tn] + (size_t)bb * NN * 32;
#pragma unroll
    for (int j = 0; j < 2; ++j)
#pragma unroll
      for (int f = 0; f < 8; ++f) {
        const int gy = by0 + 2 * w + (f >> 2);
        const int gx = bx0 + 16 * (f & 3) + l15;
        const int co0 = 16 * j + ch * 4;
        const size_t base = (size_t)(gy * N + gx) * 32 + co0;
        float4 r = *(const float4*)(rb + base);
        float o[4] = {acc[j][f][0] + r.x, acc[j][f][1] + r.y,
                      acc[j][f][2] + r.z, acc[j][f][3] + r.w};
        *(float4*)(ob + base) = *(float4*)o;
      }
  } else {
    // residual add (hrres is f32 NCHW)
#pragma unroll
    for (int j = 0; j < 2; ++j)
#pragma unroll
      for (int f = 0; f < 8; ++f) {
        const int gy = by0 + 2 * w + (f >> 2);
        const int gx = bx0 + 16 * (f & 3) + l15;
        const int co0 = 16 * j + ch * 4;
#pragma unroll
        for (int i = 0; i < 4; ++i)
          acc[j][f][i] += hrres[((size_t)(bb * 32 + co0 + i) * N + gy) * N + gx];
      }
    __syncthreads();  // tile reads done; reuse LDS as hb buffer
#pragma unroll
    for (int j = 0; j < 2; ++j)
#pragma unroll
      for (int f = 0; f < 8; ++f) {
        const int rl = 2 * w + (f >> 2);
        const int xl = 16 * (f & 3) + l15;
        const int co0 = 16 * j + ch * 4;
        unsigned short o[4];
#pragma unroll
        for (int i = 0; i < 4; ++i) o[i] = f2bf(acc[j][f][i]);
        int byt = ((rl * 4096 + xl * 64 + ((co0 >> 3) << 4)) ^ ((xl & 7) << 4)) + (co0 & 7) * 2;
        *(uint2*)(smem + byt) = *(uint2*)o;
      }
    __syncthreads();
    bfv8 whka = *(bfv8*)(smem + CTILE + 18432 + l15 * 64 + ch * 16);  // row=ct, k=ci
    float4 bv = *(const float4*)(bhk + ch * 4);
    unsigned short* S3 = outb.p[0];
#pragma unroll
    for (int f = 0; f < 8; ++f) {
      const int rl = 2 * w + (f >> 2);
      const int xl = 16 * (f & 3) + l15;
      const int byt = (rl * 4096 + xl * 64 + ch * 16) ^ ((xl & 7) << 4);
      bfv8 b = *(bfv8*)(smem + byt);
      f4v a2 = __builtin_amdgcn_mfma_f32_16x16x32_bf16(whka, b, (f4v){0.f, 0.f, 0.f, 0.f}, 0, 0, 0);
      const int gy = by0 + rl, gx = bx0 + xl;
      unsigned short o[4] = {f2bf(a2[0] + bv.x), f2bf(a2[1] + bv.y),
                             f2bf(a2[2] + bv.z), f2bf(a2[3] + bv.w)};
      *(uint2*)(S3 + (size_t)bb * ((size_t)NN * 16) + (size_t)(gy * N + gx) * 16 + ch * 4) = *(uint2*)o;
    }
  }
}

// ---------------- 1x1 conv 32->16, CL in; QT f32 out, S1/S2 bf16 out ----------------
__global__ __launch_bounds__(256) void conv1x1_16_kernel(
    F3 xs, const float* __restrict__ wq, const float* __restrict__ bq,
    const float* __restrict__ wk, const float* __restrict__ bk,
    float* __restrict__ qt, unsigned short* __restrict__ s1b,
    unsigned short* __restrict__ s2b)
{
  int tn = blockIdx.y;
  const float* w = tn == 0 ? wq : wk;
  const float* bias = tn == 0 ? bq : bk;
  int p = blockIdx.x * 256 + threadIdx.x;  // [0, 32768)
  const float* xb = xs.p[tn] + (size_t)p * 32;
  float in[32];
#pragma unroll
  for (int q = 0; q < 8; ++q) ((float4*)in)[q] = ((const float4*)xb)[q];
  float o[16];
#pragma unroll
  for (int ct = 0; ct < 16; ++ct) {
    float s = bias[ct];
#pragma unroll
    for (int c = 0; c < 32; ++c) s = fmaf(w[ct * 32 + c], in[c], s);
    o[ct] = s;
  }
  if (tn == 0) {
    float4* op = (float4*)(qt + (size_t)p * 16);
#pragma unroll
    for (int q = 0; q < 4; ++q) op[q] = ((float4*)o)[q];
  } else {
    unsigned short v[16];
#pragma unroll
    for (int i = 0; i < 16; ++i) v[i] = f2bf(o[i]);
    uint4* op = (uint4*)((tn == 1 ? s1b : s2b) + (size_t)p * 16);
    op[0] = ((uint4*)v)[0];
    op[1] = ((uint4*)v)[1];
  }
}

// ---------------- fepam: wave64 per query; K bf16; LDS transpose-reduce PV ----
__global__ __launch_bounds__(256) void fepam_kernel(
    const float* __restrict__ Qt, const unsigned short* __restrict__ St,
    const unsigned short* __restrict__ Rt, const int* __restrict__ px,
    const int* __restrict__ py, const int* __restrict__ idxflag,
    float* __restrict__ out, int Ws, int HWs)
{
  __shared__ unsigned pv[4][64][17];  // pitch 17 dwords: 2-way bank alias only
  const int wv = threadIdx.x >> 6;
  const int lane = threadIdx.x & 63;
  const int wid = (blockIdx.x * 256 + threadIdx.x) >> 6;
  const int bb = wid >> 14;
  const int f = *idxflag;
  const int j = (wid * 64 + lane) << f;
  const int sidx = px[j] * Ws + py[j];

  // gathers (issue both before any cross-lane work)
  const unsigned short* kp = St + ((size_t)bb * HWs + sidx) * 16;
  unsigned kk[8];
  ((uint4*)kk)[0] = ((const uint4*)kp)[0];
  ((uint4*)kk)[1] = ((const uint4*)kp)[1];
  const unsigned short* vp = Rt + ((size_t)bb * HWs + sidx) * 32;
  unsigned vv[16];
#pragma unroll
  for (int q = 0; q < 4; ++q) ((uint4*)vv)[q] = ((const uint4*)vp)[q];

  const float* qp = Qt + (size_t)wid * 16;
  float qreg[16];
#pragma unroll
  for (int q = 0; q < 4; ++q) ((float4*)qreg)[q] = ((const float4*)qp)[q];

  float score = 0.f;
#pragma unroll
  for (int i = 0; i < 8; ++i) {
    score = fmaf(qreg[2 * i],     __uint_as_float(kk[i] << 16), score);
    score = fmaf(qreg[2 * i + 1], __uint_as_float(kk[i] & 0xFFFF0000u), score);
  }
  // scores are bounded << 80 (weights ~0.05); skip max-subtract, clamp for safety
  float e = __expf(fminf(score, 80.f));
  float s = e;
#pragma unroll
  for (int off = 32; off; off >>= 1) s += __shfl_xor(s, off);

  // premultiplied packed-bf16 products -> LDS row `lane`
#pragma unroll
  for (int i = 0; i < 16; ++i) {
    float plo = e * __uint_as_float(vv[i] << 16);
    float phi = e * __uint_as_float(vv[i] & 0xFFFF0000u);
    unsigned ulo = __float_as_uint(plo) + 0x8000u;
    unsigned uhi = __float_as_uint(phi) + 0x8000u;
    pv[wv][lane][i] = (ulo >> 16) | (uhi & 0xFFFF0000u);
  }
  __syncthreads();

  // transpose-read: lane -> channel c = lane&31, row-half h = lane>>5
  const int c = lane & 31, h = lane >> 5;
  const int wsel = c >> 1;
  const unsigned sh = (c & 1) ? 0u : 16u;  // hi half sits in top bits already
  float val = 0.f;
#pragma unroll
  for (int i = 0; i < 32; ++i) {
    unsigned u = pv[wv][h * 32 + i][wsel];
    val += __uint_as_float((u << sh) & 0xFFFF0000u);
  }
  val += __shfl_xor(val, 32);
  if (lane < 32) out[(size_t)wid * 32 + c] = val / s;
}

// ---------------- final 1x1 over concat(b1,b2,b3,lb0 CL) -> f32 NCHW ----------------
__global__ __launch_bounds__(256) void final_conv_kernel(
    const float* __restrict__ bt1, const float* __restrict__ bt2,
    const float* __restrict__ bt3, const float* __restrict__ lb0,
    const float* __restrict__ wf, const float* __restrict__ bfb,
    float* __restrict__ out)
{
  int p = blockIdx.x * 256 + threadIdx.x;
  int bb = p >> 14, pp = p & 16383;
  float in[128];
#pragma unroll
  for (int q = 0; q < 8; ++q) ((float4*)in)[q]        = ((const float4*)(bt1 + (size_t)p * 32))[q];
#pragma unroll
  for (int q = 0; q < 8; ++q) ((float4*)(in + 32))[q] = ((const float4*)(bt2 + (size_t)p * 32))[q];
#pragma unroll
  for (int q = 0; q < 8; ++q) ((float4*)(in + 64))[q] = ((const float4*)(bt3 + (size_t)p * 32))[q];
#pragma unroll
  for (int q = 0; q < 8; ++q) ((float4*)(in + 96))[q] = ((const float4*)(lb0 + (size_t)p * 32))[q];
#pragma unroll 2
  for (int co = 0; co < 32; ++co) {
    float s = bfb[co];
#pragma unroll
    for (int c = 0; c < 128; ++c) s = fmaf(wf[co * 128 + c], in[c], s);
    out[((size_t)bb * 32 + co) * 16384 + pp] = s;
  }
}

extern "C" void kernel_launch(void* const* d_in, const int* in_sizes, int n_in,
                              void* d_out, int out_size, void* d_ws, size_t ws_size,
                              hipStream_t stream)
{
  const float* lr0 = (const float*)d_in[0];
  const float* lr1 = (const float*)d_in[1];
  const float* lr2 = (const float*)d_in[2];
  const float* hr  = (const float*)d_in[3];
  const float* wl1 = (const float*)d_in[4];
  const float* wl2 = (const float*)d_in[5];
  const float* wh1 = (const float*)d_in[6];
  const float* wh2 = (const float*)d_in[7];
  const float* wq  = (const float*)d_in[8];
  const float* bq  = (const float*)d_in[9];
  const float* wk  = (const float*)d_in[10];
  const float* bk  = (const float*)d_in[11];
  const float* whk = (const float*)d_in[12];
  const float* bhk = (const float*)d_in[13];
  const float* wf  = (const float*)d_in[14];
  const float* bf  = (const float*)d_in[15];
  const int* px0 = (const int*)d_in[16];
  const int* py0 = (const int*)d_in[17];
  const int* px1 = (const int*)d_in[18];
  const int* py1 = (const int*)d_in[19];
  const int* px2 = (const int*)d_in[20];
  const int* py2 = (const int*)d_in[21];
  float* out = (float*)d_out;
  float* ws = (float*)d_ws;

  unsigned short* S3B = (unsigned short*)ws;
  unsigned short* YC  = (unsigned short*)(ws + 8388608);   // hr intermediate
  unsigned short* YLC = (unsigned short*)(ws + 8388608);   // lr intermediate (dead before YC)
  float* R0T = ws + 9961472;
  float* R1T = ws + 11010048;
  float* R2T = ws + 12058624;
  unsigned short* LRC = (unsigned short*)(ws + 13107200);  // bf16 CL lr0/1/2 (dead before YC)
  unsigned short* HRC = (unsigned short*)(ws + 16777216);
  float* LB0 = ws + 25165824;
  float* LB1 = ws + 26214400;
  float* LB2 = ws + 27262976;
  float* QT  = ws + 29360128;
  unsigned short* S1B = (unsigned short*)(ws + 29884416);
  unsigned short* S2B = (unsigned short*)(ws + 30408704);
  float* BT1 = ws + 33030144;
  float* BT2 = ws + 34078720;
  float* BT3 = ws + 35127296;
  unsigned short* WBL1 = (unsigned short*)(ws + 36175872);
  unsigned short* WBL2 = (unsigned short*)(ws + 36180480);
  unsigned short* WBH1 = (unsigned short*)(ws + 36185088);
  unsigned short* WBH2 = (unsigned short*)(ws + 36189696);
  unsigned short* WHKB = (unsigned short*)(ws + 36194304);
  int* IDXFLAG = (int*)(ws + 36194560);

  unsigned short* LRC0 = LRC;
  unsigned short* LRC1 = LRC + 1048576;
  unsigned short* LRC2 = LRC + 2097152;
  unsigned short* YLC0 = YLC;
  unsigned short* YLC1 = YLC + 1048576;
  unsigned short* YLC2 = YLC + 2097152;

  F3 fnone{};
  OB3 obnone{};
  OF3 ofnone{};

  // prep
  idx_detect_kernel<<<1, 256, 0, stream>>>(px0, IDXFLAG);
  wconv_bf16_kernel<<<dim3(36, 5), 256, 0, stream>>>(wl1, wl2, wh1, wh2, whk,
                                                     WBL1, WBL2, WBH1, WBH2, WHKB);
  lrprep_kernel<<<dim3(128, 3), 256, 0, stream>>>(
      F3{{lr0, lr1, lr2}}, OF3{{R0T, R1T, R2T}}, OB3{{LRC0, LRC1, LRC2}});
  hrc_kernel<<<2048, 256, 0, stream>>>(hr, HRC);

  // lr resb via MFMA (batched 3 tensors)
  conv_mfma_kernel<128, 0><<<dim3(2, 16, 6), 256, 0, stream>>>(
      B3{{LRC0, LRC1, LRC2}}, WBL1, fnone, nullptr, nullptr, nullptr,
      OB3{{YLC0, YLC1, YLC2}}, ofnone);
  conv_mfma_kernel<128, 1><<<dim3(2, 16, 6), 256, 0, stream>>>(
      B3{{YLC0, YLC1, YLC2}}, WBL2, F3{{R0T, R1T, R2T}}, nullptr, nullptr, nullptr,
      obnone, OF3{{LB0, LB1, LB2}});

  // projections (QT f32, S1/S2 bf16), batched
  conv1x1_16_kernel<<<dim3(128, 3), 256, 0, stream>>>(
      F3{{LB0, LB1, LB2}}, wq, bq, wk, bk, QT, S1B, S2B);

  // fepam 1/2 (V from LRC bf16) — before YC overwrites the lr temp region
  fepam_kernel<<<8192, 256, 0, stream>>>(QT, S1B, LRC1, px0, py0, IDXFLAG, BT1, 128, 16384);
  fepam_kernel<<<8192, 256, 0, stream>>>(QT, S2B, LRC2, px1, py1, IDXFLAG, BT2, 128, 16384);

  // hr resb via MFMA; S3 (bf16) fused; hb never materialized
  conv_mfma_kernel<512, 0><<<dim3(8, 64, 2), 256, 0, stream>>>(
      B3{{HRC}}, WBH1, fnone, nullptr, nullptr, nullptr, OB3{{YC}}, ofnone);
  conv_mfma_kernel<512, 2><<<dim3(8, 64, 2), 256, 0, stream>>>(
      B3{{YC}}, WBH2, fnone, hr, WHKB, bhk, OB3{{S3B}}, ofnone);

  // fepam 3 (V from HRC bf16)
  fepam_kernel<<<8192, 256, 0, stream>>>(QT, S3B, HRC, px2, py2, IDXFLAG, BT3, 512, 262144);

  // final fuse
  final_conv_kernel<<<128, 256, 0, stream>>>(BT1, BT2, BT3, LB0, wf, bf, out);
}

// Round 9
// 276.433 us; speedup vs baseline: 6.5639x; 1.1491x over previous
//
#include <hip/hip_runtime.h>
#include <hip/hip_bf16.h>

typedef short bfv8 __attribute__((ext_vector_type(8)));
typedef float f4v __attribute__((ext_vector_type(4)));

static __device__ __forceinline__ unsigned short f2bf(float f) {
  unsigned u = __float_as_uint(f);
  unsigned r = (u + 0x7FFFu + ((u >> 16) & 1u)) >> 16;
  return (unsigned short)r;
}
static __device__ __forceinline__ unsigned pack2bf(float lo, float hi) {
  return (unsigned)f2bf(lo) | ((unsigned)f2bf(hi) << 16);
}

// Workspace (float offsets):
// S3B bf16 (2,512,512,16) @0..4194304
// YC  (hr intermediate bf16 CL) @8388608..16777216
//   aliased lr temporaries (dead before YC written):
//   YLC bf16 @8388608 | R0T @9961472 | R1T @11010048 | R2T @12058624 | LRC bf16 @13107200
// HRC (hr bf16 CL) @16777216..25165824
// LB0/1/2 f32 CL @25165824/26214400/27262976
// QT f32 CL16 @29360128 ; S1B/S2B bf16 CL16 @29884416/30408704
// BT1/2/3 f32 CL32 @33030144/34078720/35127296
// WBL1/WBL2/WBH1/WBH2 bf16 @36175872/+4608/+9216/+13824 ; WHKB @+18432 ; IDXFLAG @+18720

struct B3  { const unsigned short* p[3]; };
struct F3  { const float* p[3]; };
struct OB3 { unsigned short* p[3]; };
struct OF3 { float* p[3]; };

// ---------------- index-dtype probe ----------------
__global__ void idx_detect_kernel(const int* __restrict__ px, int* __restrict__ flag) {
  __shared__ int s;
  if (threadIdx.x == 0) s = 0;
  __syncthreads();
  int v = px[2 * threadIdx.x + 1];
  if (v != 0) atomicOr(&s, 1);
  __syncthreads();
  if (threadIdx.x == 0) *flag = (s == 0) ? 1 : 0;  // 1 => int64, 0 => int32
}

// ---------------- bf16 weight prep: [co][ci][3][3] -> [tap][co][ci]; y==4: whk ----
__global__ __launch_bounds__(256) void wconv_bf16_kernel(
    const float* __restrict__ wl1, const float* __restrict__ wl2,
    const float* __restrict__ wh1, const float* __restrict__ wh2,
    const float* __restrict__ whk,
    unsigned short* __restrict__ ol1, unsigned short* __restrict__ ol2,
    unsigned short* __restrict__ oh1, unsigned short* __restrict__ oh2,
    unsigned short* __restrict__ ok)
{
  int i = blockIdx.x * 256 + threadIdx.x;
  int y = blockIdx.y;
  if (y < 4) {
    const float* w = y == 0 ? wl1 : y == 1 ? wl2 : y == 2 ? wh1 : wh2;
    unsigned short* o = y == 0 ? ol1 : y == 1 ? ol2 : y == 2 ? oh1 : oh2;
    if (i < 9216) {
      int t = i / 1024, rem = i % 1024, co = rem >> 5, ci = rem & 31;
      o[i] = f2bf(w[(co * 32 + ci) * 9 + t]);
    }
  } else if (i < 512) {
    ok[i] = f2bf(whk[i]);
  }
}

// ---------------- hr NCHW f32 -> channel-last bf16 ----------------
__global__ __launch_bounds__(256) void hrc_kernel(
    const float* __restrict__ x, unsigned short* __restrict__ o)
{
  int p = blockIdx.x * 256 + threadIdx.x;  // [0, 524288)
  int bb = p >> 18, pp = p & 262143;
  const float* xb = x + ((size_t)bb * 32) * 262144 + pp;
  unsigned short v[32];
#pragma unroll
  for (int c = 0; c < 32; ++c) v[c] = f2bf(xb[(size_t)c * 262144]);
  uint4* op = (uint4*)(o + (size_t)p * 32);
#pragma unroll
  for (int q = 0; q < 4; ++q) op[q] = ((uint4*)v)[q];
}

// ---------------- lr prep: NCHW f32 -> CL f32 (R*T) + CL bf16 (LRC) ----------------
__global__ __launch_bounds__(256) void lrprep_kernel(
    F3 xs, OF3 of, OB3 ob)
{
  int tn = blockIdx.y;
  int p = blockIdx.x * 256 + threadIdx.x;  // [0, 32768)
  int bb = p >> 14, pp = p & 16383;
  const float* xb = xs.p[tn] + ((size_t)bb * 32) * 16384 + pp;
  float o[32];
  unsigned short v[32];
#pragma unroll
  for (int c = 0; c < 32; ++c) { o[c] = xb[(size_t)c * 16384]; v[c] = f2bf(o[c]); }
  float4* op = (float4*)(of.p[tn] + (size_t)p * 32);
#pragma unroll
  for (int q = 0; q < 8; ++q) op[q] = ((float4*)o)[q];
  uint4* bp = (uint4*)(ob.p[tn] + (size_t)p * 32);
#pragma unroll
  for (int q = 0; q < 4; ++q) bp[q] = ((uint4*)v)[q];
}

// ---------------- MFMA 3x3 conv, bf16 channel-last ----------------
// Block: 8 rows x 64 cols, 4 waves; wave w: rows 2w..2w+1 (128 px x 32 co).
// MODE 0: outb = lrelu(conv)                (bf16 CL)
// MODE 1: outf = conv + res (f32 CL)        (f32 CL)
// MODE 2: hb = conv + hrres (f32 NCHW); outb.p[0] = bf16(whk*hb + bhk) (CL 16ch)
#define CTILE 42240  // 10 rows x 66 px x 64B
template <int N, int MODE>
__global__ __launch_bounds__(256, 2) void conv_mfma_kernel(
    B3 xs, const unsigned short* __restrict__ WB, F3 res,
    const float* __restrict__ hrres, const unsigned short* __restrict__ WHKB,
    const float* __restrict__ bhk, OB3 outb, OF3 outf)
{
  __shared__ uint4 smem_[3856];  // 61696 B: tile 42240 | conv W 18432 | whk 1024
  unsigned char* smem = (unsigned char*)smem_;
  const int NN = N * N;
  const int bx0 = blockIdx.x * 64, by0 = blockIdx.y * 8;
  const int tn = (N == 512) ? 0 : (blockIdx.z >> 1);
  const int bb = (N == 512) ? blockIdx.z : (blockIdx.z & 1);
  const int tid = threadIdx.x;
  const int w = tid >> 6, lane = tid & 63;
  const int l15 = lane & 15, ch = lane >> 4;

  // stage input tile (rows by0-1..by0+8, px bx0-1..bx0+64, 32ch bf16), XOR-swizzled
  const unsigned short* Xb = xs.p[tn] + (size_t)bb * NN * 32;
  for (int g = tid; g < 2640; g += 256) {
    int row = g / 264, rem = g - row * 264;
    int px = rem >> 2, c4 = rem & 3;
    int gy = by0 + row - 1, gx = bx0 + px - 1;
    uint4 v = {0u, 0u, 0u, 0u};
    if (gy >= 0 && gy < N && gx >= 0 && gx < N)
      v = *(const uint4*)(Xb + (size_t)(gy * N + gx) * 32 + c4 * 8);
    int byt = (row * 4224 + px * 64 + c4 * 16) ^ ((px & 7) << 4);
    *(uint4*)(smem + byt) = v;
  }
  for (int g = tid; g < 1152; g += 256)
    *(uint4*)(smem + CTILE + g * 16) = *(const uint4*)(WB + g * 8);
  if (MODE == 2) {
    if (tid < 64)
      *(uint4*)(smem + CTILE + 18432 + tid * 16) = *(const uint4*)(WHKB + tid * 8);
  }
  __syncthreads();

  // weight A-fragments (row = co, k = ci)
  bfv8 wa[9][2];
#pragma unroll
  for (int t = 0; t < 9; ++t)
#pragma unroll
    for (int j = 0; j < 2; ++j)
      wa[t][j] = *(bfv8*)(smem + CTILE + t * 2048 + (16 * j + l15) * 64 + ch * 16);

  f4v acc[2][8];
#pragma unroll
  for (int j = 0; j < 2; ++j)
#pragma unroll
    for (int f = 0; f < 8; ++f) acc[j][f] = (f4v){0.f, 0.f, 0.f, 0.f};

#pragma unroll
  for (int dy = 0; dy < 3; ++dy)
#pragma unroll
    for (int dx = 0; dx < 3; ++dx)
#pragma unroll
      for (int f = 0; f < 8; ++f) {
        const int hrow = 2 * w + (f >> 2) + dy;
        const int xh = 16 * (f & 3) + l15 + dx;
        const int byt = (hrow * 4224 + xh * 64 + ch * 16) ^ ((xh & 7) << 4);
        bfv8 b = *(bfv8*)(smem + byt);
        acc[0][f] = __builtin_amdgcn_mfma_f32_16x16x32_bf16(wa[dy * 3 + dx][0], b, acc[0][f], 0, 0, 0);
        acc[1][f] = __builtin_amdgcn_mfma_f32_16x16x32_bf16(wa[dy * 3 + dx][1], b, acc[1][f], 0, 0, 0);
      }

  // D layout: col(px) = l15, row(co within frag) = ch*4+i
  if (MODE == 0) {
    unsigned short* ob = outb.p[tn] + (size_t)bb * NN * 32;
#pragma unroll
    for (int j = 0; j < 2; ++j)
#pragma unroll
      for (int f = 0; f < 8; ++f) {
        const int gy = by0 + 2 * w + (f >> 2);
        const int gx = bx0 + 16 * (f & 3) + l15;
        const int co0 = 16 * j + ch * 4;
        unsigned short o[4];
#pragma unroll
        for (int i = 0; i < 4; ++i) {
          float a = acc[j][f][i];
          a = a > 0.f ? a : 0.1f * a;
          o[i] = f2bf(a);
        }
        *(uint2*)(ob + (size_t)(gy * N + gx) * 32 + co0) = *(uint2*)o;
      }
  } else if (MODE == 1) {
    const float* rb = res.p[tn] + (size_t)bb * NN * 32;
    float* ob = outf.p[tn] + (size_t)bb * NN * 32;
#pragma unroll
    for (int j = 0; j < 2; ++j)
#pragma unroll
      for (int f = 0; f < 8; ++f) {
        const int gy = by0 + 2 * w + (f >> 2);
        const int gx = bx0 + 16 * (f & 3) + l15;
        const int co0 = 16 * j + ch * 4;
        const size_t base = (size_t)(gy * N + gx) * 32 + co0;
        float4 r = *(const float4*)(rb + base);
        float o[4] = {acc[j][f][0] + r.x, acc[j][f][1] + r.y,
                      acc[j][f][2] + r.z, acc[j][f][3] + r.w};
        *(float4*)(ob + base) = *(float4*)o;
      }
  } else {
    // residual add (hrres is f32 NCHW)
#pragma unroll
    for (int j = 0; j < 2; ++j)
#pragma unroll
      for (int f = 0; f < 8; ++f) {
        const int gy = by0 + 2 * w + (f >> 2);
        const int gx = bx0 + 16 * (f & 3) + l15;
        const int co0 = 16 * j + ch * 4;
#pragma unroll
        for (int i = 0; i < 4; ++i)
          acc[j][f][i] += hrres[((size_t)(bb * 32 + co0 + i) * N + gy) * N + gx];
      }
    __syncthreads();  // tile reads done; reuse LDS as hb buffer
#pragma unroll
    for (int j = 0; j < 2; ++j)
#pragma unroll
      for (int f = 0; f < 8; ++f) {
        const int rl = 2 * w + (f >> 2);
        const int xl = 16 * (f & 3) + l15;
        const int co0 = 16 * j + ch * 4;
        unsigned short o[4];
#pragma unroll
        for (int i = 0; i < 4; ++i) o[i] = f2bf(acc[j][f][i]);
        int byt = ((rl * 4096 + xl * 64 + ((co0 >> 3) << 4)) ^ ((xl & 7) << 4)) + (co0 & 7) * 2;
        *(uint2*)(smem + byt) = *(uint2*)o;
      }
    __syncthreads();
    bfv8 whka = *(bfv8*)(smem + CTILE + 18432 + l15 * 64 + ch * 16);  // row=ct, k=ci
    float4 bv = *(const float4*)(bhk + ch * 4);
    unsigned short* S3 = outb.p[0];
#pragma unroll
    for (int f = 0; f < 8; ++f) {
      const int rl = 2 * w + (f >> 2);
      const int xl = 16 * (f & 3) + l15;
      const int byt = (rl * 4096 + xl * 64 + ch * 16) ^ ((xl & 7) << 4);
      bfv8 b = *(bfv8*)(smem + byt);
      f4v a2 = __builtin_amdgcn_mfma_f32_16x16x32_bf16(whka, b, (f4v){0.f, 0.f, 0.f, 0.f}, 0, 0, 0);
      const int gy = by0 + rl, gx = bx0 + xl;
      unsigned short o[4] = {f2bf(a2[0] + bv.x), f2bf(a2[1] + bv.y),
                             f2bf(a2[2] + bv.z), f2bf(a2[3] + bv.w)};
      *(uint2*)(S3 + (size_t)bb * ((size_t)NN * 16) + (size_t)(gy * N + gx) * 16 + ch * 4) = *(uint2*)o;
    }
  }
}

// ---------------- 1x1 conv 32->16, CL in; QT f32 out, S1/S2 bf16 out ----------------
__global__ __launch_bounds__(256) void conv1x1_16_kernel(
    F3 xs, const float* __restrict__ wq, const float* __restrict__ bq,
    const float* __restrict__ wk, const float* __restrict__ bk,
    float* __restrict__ qt, unsigned short* __restrict__ s1b,
    unsigned short* __restrict__ s2b)
{
  int tn = blockIdx.y;
  const float* w = tn == 0 ? wq : wk;
  const float* bias = tn == 0 ? bq : bk;
  int p = blockIdx.x * 256 + threadIdx.x;  // [0, 32768)
  const float* xb = xs.p[tn] + (size_t)p * 32;
  float in[32];
#pragma unroll
  for (int q = 0; q < 8; ++q) ((float4*)in)[q] = ((const float4*)xb)[q];
  float o[16];
#pragma unroll
  for (int ct = 0; ct < 16; ++ct) {
    float s = bias[ct];
#pragma unroll
    for (int c = 0; c < 32; ++c) s = fmaf(w[ct * 32 + c], in[c], s);
    o[ct] = s;
  }
  if (tn == 0) {
    float4* op = (float4*)(qt + (size_t)p * 16);
#pragma unroll
    for (int q = 0; q < 4; ++q) op[q] = ((float4*)o)[q];
  } else {
    unsigned short v[16];
#pragma unroll
    for (int i = 0; i < 16; ++i) v[i] = f2bf(o[i]);
    uint4* op = (uint4*)((tn == 1 ? s1b : s2b) + (size_t)p * 16);
    op[0] = ((uint4*)v)[0];
    op[1] = ((uint4*)v)[1];
  }
}

// ---------------- fepam: wave64 per query; K bf16; LDS transpose-reduce PV ----
__global__ __launch_bounds__(256) void fepam_kernel(
    const float* __restrict__ Qt, const unsigned short* __restrict__ St,
    const unsigned short* __restrict__ Rt, const int* __restrict__ px,
    const int* __restrict__ py, const int* __restrict__ idxflag,
    float* __restrict__ out, int Ws, int HWs)
{
  __shared__ unsigned pv[4][64][17];  // pitch 17 dwords: 2-way bank alias only
  const int wv = threadIdx.x >> 6;
  const int lane = threadIdx.x & 63;
  const int wid = (blockIdx.x * 256 + threadIdx.x) >> 6;
  const int bb = wid >> 14;
  const int f = *idxflag;
  const int j = (wid * 64 + lane) << f;
  const int sidx = px[j] * Ws + py[j];

  // gathers (issue both before any cross-lane work)
  const unsigned short* kp = St + ((size_t)bb * HWs + sidx) * 16;
  unsigned kk[8];
  ((uint4*)kk)[0] = ((const uint4*)kp)[0];
  ((uint4*)kk)[1] = ((const uint4*)kp)[1];
  const unsigned short* vp = Rt + ((size_t)bb * HWs + sidx) * 32;
  unsigned vv[16];
#pragma unroll
  for (int q = 0; q < 4; ++q) ((uint4*)vv)[q] = ((const uint4*)vp)[q];

  const float* qp = Qt + (size_t)wid * 16;
  float qreg[16];
#pragma unroll
  for (int q = 0; q < 4; ++q) ((float4*)qreg)[q] = ((const float4*)qp)[q];

  float score = 0.f;
#pragma unroll
  for (int i = 0; i < 8; ++i) {
    score = fmaf(qreg[2 * i],     __uint_as_float(kk[i] << 16), score);
    score = fmaf(qreg[2 * i + 1], __uint_as_float(kk[i] & 0xFFFF0000u), score);
  }
  // scores are bounded << 80 (weights ~0.05); skip max-subtract, clamp for safety
  float e = __expf(fminf(score, 80.f));
  float s = e;
#pragma unroll
  for (int off = 32; off; off >>= 1) s += __shfl_xor(s, off);

  // premultiplied packed-bf16 products -> LDS row `lane`
#pragma unroll
  for (int i = 0; i < 16; ++i) {
    float plo = e * __uint_as_float(vv[i] << 16);
    float phi = e * __uint_as_float(vv[i] & 0xFFFF0000u);
    unsigned ulo = __float_as_uint(plo) + 0x8000u;
    unsigned uhi = __float_as_uint(phi) + 0x8000u;
    pv[wv][lane][i] = (ulo >> 16) | (uhi & 0xFFFF0000u);
  }
  __syncthreads();

  // transpose-read: lane -> channel c = lane&31, row-half h = lane>>5
  const int c = lane & 31, h = lane >> 5;
  const int wsel = c >> 1;
  const unsigned sh = (c & 1) ? 0u : 16u;  // hi half sits in top bits already
  float val = 0.f;
#pragma unroll
  for (int i = 0; i < 32; ++i) {
    unsigned u = pv[wv][h * 32 + i][wsel];
    val += __uint_as_float((u << sh) & 0xFFFF0000u);
  }
  val += __shfl_xor(val, 32);
  if (lane < 32) out[(size_t)wid * 32 + c] = val / s;
}

// ---------------- final 1x1 (GEMM 32co x 64px, K=128) via MFMA -> f32 NCHW ----------
// LDS: in_s [64px][128k] bf16 @0 (16KB), wf_s [32co][128k] bf16 @16384 (8KB),
// bias f32 @24576. XOR swizzle ^((row&7)<<4) on both.
__global__ __launch_bounds__(256) void final_conv_kernel(
    const float* __restrict__ bt1, const float* __restrict__ bt2,
    const float* __restrict__ bt3, const float* __restrict__ lb0,
    const float* __restrict__ wf, const float* __restrict__ bfb,
    float* __restrict__ out)
{
  __shared__ uint4 smem_[1544];  // 24704 B
  unsigned char* smem = (unsigned char*)smem_;
  const int tid = threadIdx.x;
  const int px0 = blockIdx.x * 64;

  // stage inputs: thread -> px = tid>>2, 8 floats at k = q*32 + (tid&3)*8
  {
    const int pxl = tid >> 2, c0 = (tid & 3) * 8;
    const float* srcs[4] = {bt1, bt2, bt3, lb0};
#pragma unroll
    for (int q = 0; q < 4; ++q) {
      const float* sp = srcs[q] + (size_t)(px0 + pxl) * 32 + c0;
      float4 a = ((const float4*)sp)[0];
      float4 b = ((const float4*)sp)[1];
      unsigned pk[4] = {pack2bf(a.x, a.y), pack2bf(a.z, a.w),
                        pack2bf(b.x, b.y), pack2bf(b.z, b.w)};
      int byt = (pxl * 256 + q * 64 + c0 * 2) ^ ((pxl & 7) << 4);
      *(uint4*)(smem + byt) = *(uint4*)pk;
    }
    // wf: thread -> co = tid>>3, 16 floats at c = (tid&7)*16
    const int co = tid >> 3, cw = (tid & 7) * 16;
    const float* wp = wf + co * 128 + cw;
    float4 w0 = ((const float4*)wp)[0], w1 = ((const float4*)wp)[1];
    float4 w2 = ((const float4*)wp)[2], w3 = ((const float4*)wp)[3];
    unsigned pk0[4] = {pack2bf(w0.x, w0.y), pack2bf(w0.z, w0.w),
                       pack2bf(w1.x, w1.y), pack2bf(w1.z, w1.w)};
    unsigned pk1[4] = {pack2bf(w2.x, w2.y), pack2bf(w2.z, w2.w),
                       pack2bf(w3.x, w3.y), pack2bf(w3.z, w3.w)};
    int b0 = 16384 + ((co * 256 + cw * 2) ^ ((co & 7) << 4));
    int b1 = 16384 + ((co * 256 + cw * 2 + 16) ^ ((co & 7) << 4));
    *(uint4*)(smem + b0) = *(uint4*)pk0;
    *(uint4*)(smem + b1) = *(uint4*)pk1;
    if (tid < 32) *(float*)(smem + 24576 + tid * 4) = bfb[tid];
  }
  __syncthreads();

  const int w = tid >> 6, lane = tid & 63;
  const int l15 = lane & 15, ch = lane >> 4;
  const int pxl = w * 16 + l15;

  f4v acc[2] = {(f4v){0.f, 0.f, 0.f, 0.f}, (f4v){0.f, 0.f, 0.f, 0.f}};
#pragma unroll
  for (int kb = 0; kb < 4; ++kb) {
    bfv8 b = *(bfv8*)(smem + ((pxl * 256 + kb * 64 + ch * 16) ^ ((pxl & 7) << 4)));
#pragma unroll
    for (int j = 0; j < 2; ++j) {
      const int co = 16 * j + l15;
      bfv8 a = *(bfv8*)(smem + 16384 + ((co * 256 + kb * 64 + ch * 16) ^ ((co & 7) << 4)));
      acc[j] = __builtin_amdgcn_mfma_f32_16x16x32_bf16(a, b, acc[j], 0, 0, 0);
    }
  }

  const int p = px0 + pxl;
  const int bb = p >> 14, pp = p & 16383;
#pragma unroll
  for (int j = 0; j < 2; ++j)
#pragma unroll
    for (int i = 0; i < 4; ++i) {
      const int co = 16 * j + ch * 4 + i;
      float bias = *(float*)(smem + 24576 + co * 4);
      out[((size_t)(bb * 32 + co)) * 16384 + pp] = acc[j][i] + bias;
    }
}

extern "C" void kernel_launch(void* const* d_in, const int* in_sizes, int n_in,
                              void* d_out, int out_size, void* d_ws, size_t ws_size,
                              hipStream_t stream)
{
  const float* lr0 = (const float*)d_in[0];
  const float* lr1 = (const float*)d_in[1];
  const float* lr2 = (const float*)d_in[2];
  const float* hr  = (const float*)d_in[3];
  const float* wl1 = (const float*)d_in[4];
  const float* wl2 = (const float*)d_in[5];
  const float* wh1 = (const float*)d_in[6];
  const float* wh2 = (const float*)d_in[7];
  const float* wq  = (const float*)d_in[8];
  const float* bq  = (const float*)d_in[9];
  const float* wk  = (const float*)d_in[10];
  const float* bk  = (const float*)d_in[11];
  const float* whk = (const float*)d_in[12];
  const float* bhk = (const float*)d_in[13];
  const float* wf  = (const float*)d_in[14];
  const float* bf  = (const float*)d_in[15];
  const int* px0 = (const int*)d_in[16];
  const int* py0 = (const int*)d_in[17];
  const int* px1 = (const int*)d_in[18];
  const int* py1 = (const int*)d_in[19];
  const int* px2 = (const int*)d_in[20];
  const int* py2 = (const int*)d_in[21];
  float* out = (float*)d_out;
  float* ws = (float*)d_ws;

  unsigned short* S3B = (unsigned short*)ws;
  unsigned short* YC  = (unsigned short*)(ws + 8388608);   // hr intermediate
  unsigned short* YLC = (unsigned short*)(ws + 8388608);   // lr intermediate (dead before YC)
  float* R0T = ws + 9961472;
  float* R1T = ws + 11010048;
  float* R2T = ws + 12058624;
  unsigned short* LRC = (unsigned short*)(ws + 13107200);  // bf16 CL lr0/1/2 (dead before YC)
  unsigned short* HRC = (unsigned short*)(ws + 16777216);
  float* LB0 = ws + 25165824;
  float* LB1 = ws + 26214400;
  float* LB2 = ws + 27262976;
  float* QT  = ws + 29360128;
  unsigned short* S1B = (unsigned short*)(ws + 29884416);
  unsigned short* S2B = (unsigned short*)(ws + 30408704);
  float* BT1 = ws + 33030144;
  float* BT2 = ws + 34078720;
  float* BT3 = ws + 35127296;
  unsigned short* WBL1 = (unsigned short*)(ws + 36175872);
  unsigned short* WBL2 = (unsigned short*)(ws + 36180480);
  unsigned short* WBH1 = (unsigned short*)(ws + 36185088);
  unsigned short* WBH2 = (unsigned short*)(ws + 36189696);
  unsigned short* WHKB = (unsigned short*)(ws + 36194304);
  int* IDXFLAG = (int*)(ws + 36194560);

  unsigned short* LRC0 = LRC;
  unsigned short* LRC1 = LRC + 1048576;
  unsigned short* LRC2 = LRC + 2097152;
  unsigned short* YLC0 = YLC;
  unsigned short* YLC1 = YLC + 1048576;
  unsigned short* YLC2 = YLC + 2097152;

  F3 fnone{};
  OB3 obnone{};
  OF3 ofnone{};

  // prep
  idx_detect_kernel<<<1, 256, 0, stream>>>(px0, IDXFLAG);
  wconv_bf16_kernel<<<dim3(36, 5), 256, 0, stream>>>(wl1, wl2, wh1, wh2, whk,
                                                     WBL1, WBL2, WBH1, WBH2, WHKB);
  lrprep_kernel<<<dim3(128, 3), 256, 0, stream>>>(
      F3{{lr0, lr1, lr2}}, OF3{{R0T, R1T, R2T}}, OB3{{LRC0, LRC1, LRC2}});
  hrc_kernel<<<2048, 256, 0, stream>>>(hr, HRC);

  // lr resb via MFMA (batched 3 tensors)
  conv_mfma_kernel<128, 0><<<dim3(2, 16, 6), 256, 0, stream>>>(
      B3{{LRC0, LRC1, LRC2}}, WBL1, fnone, nullptr, nullptr, nullptr,
      OB3{{YLC0, YLC1, YLC2}}, ofnone);
  conv_mfma_kernel<128, 1><<<dim3(2, 16, 6), 256, 0, stream>>>(
      B3{{YLC0, YLC1, YLC2}}, WBL2, F3{{R0T, R1T, R2T}}, nullptr, nullptr, nullptr,
      obnone, OF3{{LB0, LB1, LB2}});

  // projections (QT f32, S1/S2 bf16), batched
  conv1x1_16_kernel<<<dim3(128, 3), 256, 0, stream>>>(
      F3{{LB0, LB1, LB2}}, wq, bq, wk, bk, QT, S1B, S2B);

  // fepam 1/2 (V from LRC bf16) — before YC overwrites the lr temp region
  fepam_kernel<<<8192, 256, 0, stream>>>(QT, S1B, LRC1, px0, py0, IDXFLAG, BT1, 128, 16384);
  fepam_kernel<<<8192, 256, 0, stream>>>(QT, S2B, LRC2, px1, py1, IDXFLAG, BT2, 128, 16384);

  // hr resb via MFMA; S3 (bf16) fused; hb never materialized
  conv_mfma_kernel<512, 0><<<dim3(8, 64, 2), 256, 0, stream>>>(
      B3{{HRC}}, WBH1, fnone, nullptr, nullptr, nullptr, OB3{{YC}}, ofnone);
  conv_mfma_kernel<512, 2><<<dim3(8, 64, 2), 256, 0, stream>>>(
      B3{{YC}}, WBH2, fnone, hr, WHKB, bhk, OB3{{S3B}}, ofnone);

  // fepam 3 (V from HRC bf16)
  fepam_kernel<<<8192, 256, 0, stream>>>(QT, S3B, HRC, px2, py2, IDXFLAG, BT3, 512, 262144);

  // final fuse
  final_conv_kernel<<<512, 256, 0, stream>>>(BT1, BT2, BT3, LB0, wf, bf, out);
}